// Round 1
// baseline (3469.547 us; speedup 1.0000x reference)
//
#include <hip/hip_runtime.h>
#include <hip/hip_bf16.h>
#include <math.h>

// Problem constants
#define BB 4
#define WW 2048
#define TOK (BB * WW)        // 8192
#define DMODEL 256
#define DINNER 512
#define DSTATE 16
#define DTRANK 16
#define DCONV 4
#define NLAYERS 2

// ---------------------------------------------------------------------------
// Embed: h[tok][d] = x[tok] * emb_w[d] + emb_b[d]
// ---------------------------------------------------------------------------
__global__ __launch_bounds__(256) void embed_kernel(
    const float* __restrict__ x, const float* __restrict__ ew,
    const float* __restrict__ eb, float* __restrict__ h) {
  int idx = blockIdx.x * 256 + threadIdx.x;     // TOK*64 threads, 4 d each
  int tok = idx >> 6;
  int d4 = (idx & 63) * 4;
  float xv = x[tok];
  float4 w = *(const float4*)&ew[d4];
  float4 b = *(const float4*)&eb[d4];
  float4 o;
  o.x = xv * w.x + b.x;
  o.y = xv * w.y + b.y;
  o.z = xv * w.z + b.z;
  o.w = xv * w.w + b.w;
  *(float4*)&h[(size_t)tok * DMODEL + d4] = o;
}

// ---------------------------------------------------------------------------
// RMSNorm: one wave per token (256 floats = 64 lanes x float4)
// ---------------------------------------------------------------------------
__global__ __launch_bounds__(256) void rmsnorm_kernel(
    const float* __restrict__ h, const float* __restrict__ w,
    float* __restrict__ u) {
  int wave = threadIdx.x >> 6;
  int lane = threadIdx.x & 63;
  int tok = blockIdx.x * 4 + wave;
  const float* hp = h + (size_t)tok * DMODEL;
  float4 v = *(const float4*)&hp[lane * 4];
  float ss = v.x * v.x + v.y * v.y + v.z * v.z + v.w * v.w;
#pragma unroll
  for (int off = 32; off; off >>= 1) ss += __shfl_xor(ss, off, 64);
  float rs = rsqrtf(ss * (1.0f / 256.0f) + 1e-5f);
  float4 wv = *(const float4*)&w[lane * 4];
  float4 o;
  o.x = v.x * rs * wv.x;
  o.y = v.y * rs * wv.y;
  o.z = v.z * rs * wv.z;
  o.w = v.w * rs * wv.w;
  *(float4*)&u[(size_t)tok * DMODEL + lane * 4] = o;
}

// ---------------------------------------------------------------------------
// SGEMM: C[M,N] = A[M,K] * B[N,K]^T (both row-major, K-contiguous dot)
// BM=128, BN=64, BK=32, 256 threads, 8x4 per thread.
// EPI==1: C += result (residual add).
// ---------------------------------------------------------------------------
template <int EPI>
__global__ __launch_bounds__(256) void gemm_nt(
    const float* __restrict__ A, const float* __restrict__ Bw,
    float* __restrict__ C, int M, int N, int K) {
  __shared__ float As[32][128];
  __shared__ float Bs[32][64];
  int tid = threadIdx.x;
  int m0 = blockIdx.y * 128;
  int n0 = blockIdx.x * 64;
  int tx = tid & 15;
  int ty = tid >> 4;
  float acc[8][4] = {};

  for (int k0 = 0; k0 < K; k0 += 32) {
    // Load A tile 128x32: 4 float4 per thread
    {
      int r = tid >> 3;            // 0..31
      int c = (tid & 7) * 4;       // 0..28
#pragma unroll
      for (int i = 0; i < 4; i++) {
        int row = r + i * 32;
        float4 v = *(const float4*)&A[(size_t)(m0 + row) * K + k0 + c];
        As[c + 0][row] = v.x;
        As[c + 1][row] = v.y;
        As[c + 2][row] = v.z;
        As[c + 3][row] = v.w;
      }
    }
    // Load B tile 64x32: 2 float4 per thread (mask rows >= N)
    {
      int rb = tid >> 2;           // 0..63
      int cb = (tid & 3) * 8;      // 0,8,16,24
#pragma unroll
      for (int i = 0; i < 2; i++) {
        int col = cb + i * 4;
        float4 v = make_float4(0.f, 0.f, 0.f, 0.f);
        if (n0 + rb < N) v = *(const float4*)&Bw[(size_t)(n0 + rb) * K + k0 + col];
        Bs[col + 0][rb] = v.x;
        Bs[col + 1][rb] = v.y;
        Bs[col + 2][rb] = v.z;
        Bs[col + 3][rb] = v.w;
      }
    }
    __syncthreads();
#pragma unroll
    for (int kk = 0; kk < 32; kk++) {
      float4 a0 = *(const float4*)&As[kk][ty * 8];
      float4 a1 = *(const float4*)&As[kk][ty * 8 + 4];
      float4 b = *(const float4*)&Bs[kk][tx * 4];
      float av[8] = {a0.x, a0.y, a0.z, a0.w, a1.x, a1.y, a1.z, a1.w};
      float bv[4] = {b.x, b.y, b.z, b.w};
#pragma unroll
      for (int i = 0; i < 8; i++) {
#pragma unroll
        for (int j = 0; j < 4; j++) acc[i][j] = fmaf(av[i], bv[j], acc[i][j]);
      }
    }
    __syncthreads();
  }

  int n = n0 + tx * 4;
  if (n < N) {
#pragma unroll
    for (int i = 0; i < 8; i++) {
      int m = m0 + ty * 8 + i;
      float* p = &C[(size_t)m * N + n];
      float4 v = {acc[i][0], acc[i][1], acc[i][2], acc[i][3]};
      if (EPI == 1) {
        float4 o = *(const float4*)p;
        v.x += o.x; v.y += o.y; v.z += o.z; v.w += o.w;
      }
      *(float4*)p = v;
    }
  }
}

// ---------------------------------------------------------------------------
// Causal depthwise conv (D_CONV=4) + SiLU.  xc = xz[:, :, 0:512].
// One thread per (tok, 4 channels).
// ---------------------------------------------------------------------------
__global__ __launch_bounds__(256) void conv_silu_kernel(
    const float* __restrict__ xz, const float* __restrict__ cw,
    const float* __restrict__ cb, float* __restrict__ xs) {
  int idx = blockIdx.x * 256 + threadIdx.x;     // TOK*128
  int tok = idx >> 7;
  int c4 = (idx & 127) * 4;
  int b = tok >> 11;
  int t = tok & (WW - 1);
  float wch[4][4];
#pragma unroll
  for (int c = 0; c < 4; c++) {
    float4 w = *(const float4*)&cw[(c4 + c) * DCONV];
    wch[c][0] = w.x; wch[c][1] = w.y; wch[c][2] = w.z; wch[c][3] = w.w;
  }
  float4 bias = *(const float4*)&cb[c4];
  float acc[4] = {bias.x, bias.y, bias.z, bias.w};
#pragma unroll
  for (int k = 0; k < 4; k++) {
    int tt = t - 3 + k;
    if (tt >= 0) {
      float4 xv = *(const float4*)&xz[((size_t)(b * WW + tt)) * (2 * DINNER) + c4];
      acc[0] = fmaf(xv.x, wch[0][k], acc[0]);
      acc[1] = fmaf(xv.y, wch[1][k], acc[1]);
      acc[2] = fmaf(xv.z, wch[2][k], acc[2]);
      acc[3] = fmaf(xv.w, wch[3][k], acc[3]);
    }
  }
  float4 o;
  o.x = acc[0] / (1.f + __expf(-acc[0]));
  o.y = acc[1] / (1.f + __expf(-acc[1]));
  o.z = acc[2] / (1.f + __expf(-acc[2]));
  o.w = acc[3] / (1.f + __expf(-acc[3]));
  *(float4*)&xs[(size_t)tok * DINNER + c4] = o;
}

// ---------------------------------------------------------------------------
// dt projection + softplus: delta[m][n] = softplus(dbc[m][0:16] . dtw[n][:] + dtb[n])
// Block handles 16 tokens x 512 n.  dtw staged in LDS (padded rows).
// ---------------------------------------------------------------------------
__global__ __launch_bounds__(256) void dt_kernel(
    const float* __restrict__ dbc, const float* __restrict__ dtw,
    const float* __restrict__ dtb, float* __restrict__ delta) {
  __shared__ float ws[512][17];   // +1 pad breaks stride-16 bank aliasing
  __shared__ float ds[16][16];
  int tid = threadIdx.x;
  int tok0 = blockIdx.x * 16;
#pragma unroll
  for (int i = 0; i < 2; i++) {
    int r = tid * 2 + i;
#pragma unroll
    for (int j = 0; j < 4; j++) {
      float4 v = *(const float4*)&dtw[r * 16 + j * 4];
      ws[r][j * 4 + 0] = v.x;
      ws[r][j * 4 + 1] = v.y;
      ws[r][j * 4 + 2] = v.z;
      ws[r][j * 4 + 3] = v.w;
    }
  }
  if (tid < 64) {
    int m = tid >> 2, j = (tid & 3) * 4;
    *(float4*)&ds[m][j] = *(const float4*)&dbc[(size_t)(tok0 + m) * 48 + j];
  }
  __syncthreads();
#pragma unroll
  for (int pass = 0; pass < 2; pass++) {
    int n = tid + pass * 256;
    float w[16];
#pragma unroll
    for (int r = 0; r < 16; r++) w[r] = ws[n][r];
    float bias = dtb[n];
#pragma unroll
    for (int m = 0; m < 16; m++) {
      float s = bias;
#pragma unroll
      for (int r = 0; r < 16; r++) s = fmaf(ds[m][r], w[r], s);
      float sp = (s > 20.f) ? s : log1pf(expf(s));
      delta[(size_t)(tok0 + m) * DINNER + n] = sp;
    }
  }
}

// ---------------------------------------------------------------------------
// Selective scan.  16 lanes per (b,d): one lane per state s.
// h_s <- exp(delta*A[d,s])*h_s + delta*B_s*u ;  y = sum_s h_s*C_s + u*Dp
// then y *= silu(z).  128 blocks x 256 threads covers 2048 (b,d) pairs.
// ---------------------------------------------------------------------------
__global__ __launch_bounds__(256) void scan_kernel(
    const float* __restrict__ delta, const float* __restrict__ dbc,
    const float* __restrict__ xs, const float* __restrict__ xz,
    const float* __restrict__ A_log, const float* __restrict__ Dp,
    float* __restrict__ y) {
  int g = blockIdx.x * 16 + (threadIdx.x >> 4);  // 0..2047 (b,d) pair
  int s = threadIdx.x & 15;
  int b = g >> 9;
  int d = g & 511;
  float Av = -__expf(A_log[d * DSTATE + s]);
  float Dv = Dp[d];
  float h = 0.f;
  const float* dl = delta + (size_t)b * WW * DINNER + d;
  const float* us = xs + (size_t)b * WW * DINNER + d;
  const float* zb = xz + (size_t)b * WW * (2 * DINNER) + DINNER + d;
  const float* bc = dbc + (size_t)b * WW * 48;
  float* yp = y + (size_t)b * WW * DINNER + d;
  for (int t = 0; t < WW; t++) {
    float dv = dl[(size_t)t * DINNER];
    float uv = us[(size_t)t * DINNER];
    float Bv = bc[t * 48 + DTRANK + s];
    float Cv = bc[t * 48 + DTRANK + DSTATE + s];
    float dA = __expf(dv * Av);
    h = fmaf(dA, h, (dv * Bv) * uv);
    float p = h * Cv;
#pragma unroll
    for (int off = 8; off; off >>= 1) p += __shfl_xor(p, off, 16);
    if (s == 0) {
      float zv = zb[(size_t)t * (2 * DINNER)];
      float yv = fmaf(uv, Dv, p);
      yv *= zv / (1.f + __expf(-zv));
      yp[(size_t)t * DINNER] = yv;
    }
  }
}

// ---------------------------------------------------------------------------
extern "C" void kernel_launch(void* const* d_in, const int* in_sizes, int n_in,
                              void* d_out, int out_size, void* d_ws, size_t ws_size,
                              hipStream_t stream) {
  const float* x = (const float*)d_in[0];
  const float* emb_w = (const float*)d_in[1];
  const float* emb_b = (const float*)d_in[2];
  const float* in_proj_w = (const float*)d_in[3];
  const float* conv_w = (const float*)d_in[4];
  const float* conv_b = (const float*)d_in[5];
  const float* x_proj_w = (const float*)d_in[6];
  const float* dt_proj_w = (const float*)d_in[7];
  const float* dt_proj_b = (const float*)d_in[8];
  const float* A_log = (const float*)d_in[9];
  const float* Dp = (const float*)d_in[10];
  const float* out_proj_w = (const float*)d_in[11];
  const float* norm_w = (const float*)d_in[12];

  float* h = (float*)d_out;                       // (8192, 256)
  float* ws = (float*)d_ws;
  float* u = ws;                                  // 2M floats
  float* xz = u + (size_t)2 * 1024 * 1024;        // 8M floats (8192x1024)
  float* xs = xz + (size_t)8 * 1024 * 1024;       // 4M floats (8192x512)
  float* dbc = xs + (size_t)4 * 1024 * 1024;      // 8192x48
  float* delta = dbc + (size_t)512 * 1024;        // 4M floats
  float* yb = delta + (size_t)4 * 1024 * 1024;    // 4M floats

  embed_kernel<<<2048, 256, 0, stream>>>(x, emb_w, emb_b, h);

  for (int l = 0; l < NLAYERS; l++) {
    rmsnorm_kernel<<<2048, 256, 0, stream>>>(h, norm_w + l * DMODEL, u);
    // in_proj: (8192,1024) = u(8192,256) @ W(1024,256)^T
    gemm_nt<0><<<dim3(1024 / 64, 8192 / 128), 256, 0, stream>>>(
        u, in_proj_w + (size_t)l * 2 * DINNER * DMODEL, xz, TOK, 2 * DINNER, DMODEL);
    conv_silu_kernel<<<4096, 256, 0, stream>>>(
        xz, conv_w + (size_t)l * DINNER * DCONV, conv_b + (size_t)l * DINNER, xs);
    // x_proj: (8192,48) = xs(8192,512) @ W(48,512)^T
    gemm_nt<0><<<dim3(1, 8192 / 128), 256, 0, stream>>>(
        xs, x_proj_w + (size_t)l * 48 * DINNER, dbc, TOK, 48, DINNER);
    dt_kernel<<<512, 256, 0, stream>>>(
        dbc, dt_proj_w + (size_t)l * DINNER * DTRANK, dt_proj_b + (size_t)l * DINNER, delta);
    scan_kernel<<<128, 256, 0, stream>>>(
        delta, dbc, xs, xz, A_log + (size_t)l * DINNER * DSTATE, Dp + (size_t)l * DINNER, yb);
    // out_proj (+residual): h += yb(8192,512) @ W(256,512)^T
    gemm_nt<1><<<dim3(256 / 64, 8192 / 128), 256, 0, stream>>>(
        yb, out_proj_w + (size_t)l * DMODEL * DINNER, h, TOK, DMODEL, DINNER);
  }
}

// Round 2
// 955.269 us; speedup vs baseline: 3.6320x; 3.6320x over previous
//
#include <hip/hip_runtime.h>
#include <hip/hip_bf16.h>
#include <math.h>

// Problem constants
#define BB 4
#define WW 2048
#define TOK (BB * WW)        // 8192
#define DMODEL 256
#define DINNER 512
#define DSTATE 16
#define DTRANK 16
#define DCONV 4
#define NLAYERS 2
#define CHUNKS 16
#define CLEN (WW / CHUNKS)   // 128

// ---------------------------------------------------------------------------
// Embed: h[tok][d] = x[tok] * emb_w[d] + emb_b[d]
// ---------------------------------------------------------------------------
__global__ __launch_bounds__(256) void embed_kernel(
    const float* __restrict__ x, const float* __restrict__ ew,
    const float* __restrict__ eb, float* __restrict__ h) {
  int idx = blockIdx.x * 256 + threadIdx.x;     // TOK*64 threads, 4 d each
  int tok = idx >> 6;
  int d4 = (idx & 63) * 4;
  float xv = x[tok];
  float4 w = *(const float4*)&ew[d4];
  float4 b = *(const float4*)&eb[d4];
  float4 o;
  o.x = xv * w.x + b.x;
  o.y = xv * w.y + b.y;
  o.z = xv * w.z + b.z;
  o.w = xv * w.w + b.w;
  *(float4*)&h[(size_t)tok * DMODEL + d4] = o;
}

// ---------------------------------------------------------------------------
// RMSNorm: one wave per token (256 floats = 64 lanes x float4)
// ---------------------------------------------------------------------------
__global__ __launch_bounds__(256) void rmsnorm_kernel(
    const float* __restrict__ h, const float* __restrict__ w,
    float* __restrict__ u) {
  int wave = threadIdx.x >> 6;
  int lane = threadIdx.x & 63;
  int tok = blockIdx.x * 4 + wave;
  const float* hp = h + (size_t)tok * DMODEL;
  float4 v = *(const float4*)&hp[lane * 4];
  float ss = v.x * v.x + v.y * v.y + v.z * v.z + v.w * v.w;
#pragma unroll
  for (int off = 32; off; off >>= 1) ss += __shfl_xor(ss, off, 64);
  float rs = rsqrtf(ss * (1.0f / 256.0f) + 1e-5f);
  float4 wv = *(const float4*)&w[lane * 4];
  float4 o;
  o.x = v.x * rs * wv.x;
  o.y = v.y * rs * wv.y;
  o.z = v.z * rs * wv.z;
  o.w = v.w * rs * wv.w;
  *(float4*)&u[(size_t)tok * DMODEL + lane * 4] = o;
}

// ---------------------------------------------------------------------------
// SGEMM: C[M,N] = A[M,K] * B[N,K]^T (both row-major, K-contiguous dot)
// BM=128, BN=64, BK=32, 256 threads, 8x4 per thread.
// EPI==1: C += result (residual add).
// ---------------------------------------------------------------------------
template <int EPI>
__global__ __launch_bounds__(256) void gemm_nt(
    const float* __restrict__ A, const float* __restrict__ Bw,
    float* __restrict__ C, int M, int N, int K) {
  __shared__ float As[32][128];
  __shared__ float Bs[32][64];
  int tid = threadIdx.x;
  int m0 = blockIdx.y * 128;
  int n0 = blockIdx.x * 64;
  int tx = tid & 15;
  int ty = tid >> 4;
  float acc[8][4] = {};

  for (int k0 = 0; k0 < K; k0 += 32) {
    // Load A tile 128x32: 4 float4 per thread
    {
      int r = tid >> 3;            // 0..31
      int c = (tid & 7) * 4;       // 0..28
#pragma unroll
      for (int i = 0; i < 4; i++) {
        int row = r + i * 32;
        float4 v = *(const float4*)&A[(size_t)(m0 + row) * K + k0 + c];
        As[c + 0][row] = v.x;
        As[c + 1][row] = v.y;
        As[c + 2][row] = v.z;
        As[c + 3][row] = v.w;
      }
    }
    // Load B tile 64x32: 2 float4 per thread (mask rows >= N)
    {
      int rb = tid >> 2;           // 0..63
      int cb = (tid & 3) * 8;      // 0,8,16,24
#pragma unroll
      for (int i = 0; i < 2; i++) {
        int col = cb + i * 4;
        float4 v = make_float4(0.f, 0.f, 0.f, 0.f);
        if (n0 + rb < N) v = *(const float4*)&Bw[(size_t)(n0 + rb) * K + k0 + col];
        Bs[col + 0][rb] = v.x;
        Bs[col + 1][rb] = v.y;
        Bs[col + 2][rb] = v.z;
        Bs[col + 3][rb] = v.w;
      }
    }
    __syncthreads();
#pragma unroll
    for (int kk = 0; kk < 32; kk++) {
      float4 a0 = *(const float4*)&As[kk][ty * 8];
      float4 a1 = *(const float4*)&As[kk][ty * 8 + 4];
      float4 b = *(const float4*)&Bs[kk][tx * 4];
      float av[8] = {a0.x, a0.y, a0.z, a0.w, a1.x, a1.y, a1.z, a1.w};
      float bv[4] = {b.x, b.y, b.z, b.w};
#pragma unroll
      for (int i = 0; i < 8; i++) {
#pragma unroll
        for (int j = 0; j < 4; j++) acc[i][j] = fmaf(av[i], bv[j], acc[i][j]);
      }
    }
    __syncthreads();
  }

  int n = n0 + tx * 4;
  if (n < N) {
#pragma unroll
    for (int i = 0; i < 8; i++) {
      int m = m0 + ty * 8 + i;
      float* p = &C[(size_t)m * N + n];
      float4 v = {acc[i][0], acc[i][1], acc[i][2], acc[i][3]};
      if (EPI == 1) {
        float4 o = *(const float4*)p;
        v.x += o.x; v.y += o.y; v.z += o.z; v.w += o.w;
      }
      *(float4*)p = v;
    }
  }
}

// ---------------------------------------------------------------------------
// Causal depthwise conv (D_CONV=4) + SiLU.  xc = xz[:, :, 0:512].
// One thread per (tok, 4 channels).
// ---------------------------------------------------------------------------
__global__ __launch_bounds__(256) void conv_silu_kernel(
    const float* __restrict__ xz, const float* __restrict__ cw,
    const float* __restrict__ cb, float* __restrict__ xs) {
  int idx = blockIdx.x * 256 + threadIdx.x;     // TOK*128
  int tok = idx >> 7;
  int c4 = (idx & 127) * 4;
  int b = tok >> 11;
  int t = tok & (WW - 1);
  float wch[4][4];
#pragma unroll
  for (int c = 0; c < 4; c++) {
    float4 w = *(const float4*)&cw[(c4 + c) * DCONV];
    wch[c][0] = w.x; wch[c][1] = w.y; wch[c][2] = w.z; wch[c][3] = w.w;
  }
  float4 bias = *(const float4*)&cb[c4];
  float acc[4] = {bias.x, bias.y, bias.z, bias.w};
#pragma unroll
  for (int k = 0; k < 4; k++) {
    int tt = t - 3 + k;
    if (tt >= 0) {
      float4 xv = *(const float4*)&xz[((size_t)(b * WW + tt)) * (2 * DINNER) + c4];
      acc[0] = fmaf(xv.x, wch[0][k], acc[0]);
      acc[1] = fmaf(xv.y, wch[1][k], acc[1]);
      acc[2] = fmaf(xv.z, wch[2][k], acc[2]);
      acc[3] = fmaf(xv.w, wch[3][k], acc[3]);
    }
  }
  float4 o;
  o.x = acc[0] / (1.f + __expf(-acc[0]));
  o.y = acc[1] / (1.f + __expf(-acc[1]));
  o.z = acc[2] / (1.f + __expf(-acc[2]));
  o.w = acc[3] / (1.f + __expf(-acc[3]));
  *(float4*)&xs[(size_t)tok * DINNER + c4] = o;
}

// ---------------------------------------------------------------------------
// dt projection + softplus: delta[m][n] = softplus(dbc[m][0:16] . dtw[n][:] + dtb[n])
// Block handles 16 tokens x 512 n.  dtw staged in LDS (padded rows).
// ---------------------------------------------------------------------------
__global__ __launch_bounds__(256) void dt_kernel(
    const float* __restrict__ dbc, const float* __restrict__ dtw,
    const float* __restrict__ dtb, float* __restrict__ delta) {
  __shared__ float ws[512][17];   // +1 pad breaks stride-16 bank aliasing
  __shared__ float ds[16][16];
  int tid = threadIdx.x;
  int tok0 = blockIdx.x * 16;
#pragma unroll
  for (int i = 0; i < 2; i++) {
    int r = tid * 2 + i;
#pragma unroll
    for (int j = 0; j < 4; j++) {
      float4 v = *(const float4*)&dtw[r * 16 + j * 4];
      ws[r][j * 4 + 0] = v.x;
      ws[r][j * 4 + 1] = v.y;
      ws[r][j * 4 + 2] = v.z;
      ws[r][j * 4 + 3] = v.w;
    }
  }
  if (tid < 64) {
    int m = tid >> 2, j = (tid & 3) * 4;
    *(float4*)&ds[m][j] = *(const float4*)&dbc[(size_t)(tok0 + m) * 48 + j];
  }
  __syncthreads();
#pragma unroll
  for (int pass = 0; pass < 2; pass++) {
    int n = tid + pass * 256;
    float w[16];
#pragma unroll
    for (int r = 0; r < 16; r++) w[r] = ws[n][r];
    float bias = dtb[n];
#pragma unroll
    for (int m = 0; m < 16; m++) {
      float s = bias;
#pragma unroll
      for (int r = 0; r < 16; r++) s = fmaf(ds[m][r], w[r], s);
      float sp = (s > 20.f) ? s : log1pf(expf(s));
      delta[(size_t)(tok0 + m) * DINNER + n] = sp;
    }
  }
}

// ---------------------------------------------------------------------------
// Chunked selective scan.  The recurrence h[t] = dA[t]*h[t-1] + dBu[t] is
// linear, so split W into CHUNKS chunks:
//   phase1: per (b,d,chunk,s) scan from h=0 -> chunk decay P, local final L
//   phase2: per (b,d,s) serial combine over chunks -> carry-in Hin
//   phase3: rerun chunk scan seeded with Hin, emit y
// Parallelism: 2048(b,d) x 16 chunks x 16 state-lanes = 8192 waves (32/CU).
// ---------------------------------------------------------------------------
__global__ __launch_bounds__(256) void scan_phase1(
    const float* __restrict__ delta, const float* __restrict__ dbc,
    const float* __restrict__ xs, const float* __restrict__ A_log,
    float* __restrict__ Pfin, float* __restrict__ Hfin) {
  int idx = blockIdx.x * 256 + threadIdx.x;   // 524288 = (g*16+c)*16+s
  int s = idx & 15;
  int gc = idx >> 4;
  int c = gc & (CHUNKS - 1);
  int g = gc >> 4;          // 0..2047
  int b = g >> 9;
  int d = g & 511;
  float Av = -__expf(A_log[d * DSTATE + s]);
  int t0 = c * CLEN;
  const float* dl = delta + ((size_t)(b * WW + t0)) * DINNER + d;
  const float* us = xs + ((size_t)(b * WW + t0)) * DINNER + d;
  const float* bc = dbc + ((size_t)(b * WW + t0)) * 48 + DTRANK + s;
  float h = 0.f, P = 1.f;
#pragma unroll 4
  for (int t = 0; t < CLEN; t++) {
    float dv = dl[(size_t)t * DINNER];
    float uv = us[(size_t)t * DINNER];
    float Bv = bc[t * 48];
    float dA = __expf(dv * Av);
    P *= dA;
    h = fmaf(dA, h, (dv * Bv) * uv);
  }
  Pfin[idx] = P;
  Hfin[idx] = h;
}

__global__ __launch_bounds__(256) void scan_phase2(
    const float* __restrict__ Pfin, const float* __restrict__ Hfin,
    float* __restrict__ Hin) {
  int idx = blockIdx.x * 256 + threadIdx.x;  // 32768 = g*16+s
  int s = idx & 15;
  int g = idx >> 4;
  float h = 0.f;
#pragma unroll
  for (int c = 0; c < CHUNKS; c++) {
    size_t o = ((size_t)g * CHUNKS + c) * 16 + s;
    Hin[o] = h;
    h = fmaf(Pfin[o], h, Hfin[o]);
  }
}

__global__ __launch_bounds__(256) void scan_phase3(
    const float* __restrict__ delta, const float* __restrict__ dbc,
    const float* __restrict__ xs, const float* __restrict__ xz,
    const float* __restrict__ A_log, const float* __restrict__ Dp,
    const float* __restrict__ Hin, float* __restrict__ y) {
  int idx = blockIdx.x * 256 + threadIdx.x;
  int s = idx & 15;
  int gc = idx >> 4;
  int c = gc & (CHUNKS - 1);
  int g = gc >> 4;
  int b = g >> 9;
  int d = g & 511;
  float Av = -__expf(A_log[d * DSTATE + s]);
  float Dv = Dp[d];
  int t0 = c * CLEN;
  const float* dl = delta + ((size_t)(b * WW + t0)) * DINNER + d;
  const float* us = xs + ((size_t)(b * WW + t0)) * DINNER + d;
  const float* bc = dbc + ((size_t)(b * WW + t0)) * 48;
  const float* zb = xz + ((size_t)(b * WW + t0)) * (2 * DINNER) + DINNER + d;
  float* yp = y + ((size_t)(b * WW + t0)) * DINNER + d;
  float h = Hin[idx];
#pragma unroll 2
  for (int t = 0; t < CLEN; t++) {
    float dv = dl[(size_t)t * DINNER];
    float uv = us[(size_t)t * DINNER];
    float Bv = bc[t * 48 + DTRANK + s];
    float Cv = bc[t * 48 + DTRANK + DSTATE + s];
    float dA = __expf(dv * Av);
    h = fmaf(dA, h, (dv * Bv) * uv);
    float p = h * Cv;
#pragma unroll
    for (int off = 8; off; off >>= 1) p += __shfl_xor(p, off, 16);
    if (s == 0) {
      float zv = zb[(size_t)t * (2 * DINNER)];
      float yv = fmaf(uv, Dv, p);
      yv *= zv / (1.f + __expf(-zv));
      yp[(size_t)t * DINNER] = yv;
    }
  }
}

// ---------------------------------------------------------------------------
extern "C" void kernel_launch(void* const* d_in, const int* in_sizes, int n_in,
                              void* d_out, int out_size, void* d_ws, size_t ws_size,
                              hipStream_t stream) {
  const float* x = (const float*)d_in[0];
  const float* emb_w = (const float*)d_in[1];
  const float* emb_b = (const float*)d_in[2];
  const float* in_proj_w = (const float*)d_in[3];
  const float* conv_w = (const float*)d_in[4];
  const float* conv_b = (const float*)d_in[5];
  const float* x_proj_w = (const float*)d_in[6];
  const float* dt_proj_w = (const float*)d_in[7];
  const float* dt_proj_b = (const float*)d_in[8];
  const float* A_log = (const float*)d_in[9];
  const float* Dp = (const float*)d_in[10];
  const float* out_proj_w = (const float*)d_in[11];
  const float* norm_w = (const float*)d_in[12];

  float* h = (float*)d_out;                       // (8192, 256)
  float* ws = (float*)d_ws;
  float* u = ws;                                  // 2M floats (free during scan)
  float* xz = u + (size_t)2 * 1024 * 1024;        // 8M floats (8192x1024)
  float* xs = xz + (size_t)8 * 1024 * 1024;       // 4M floats (8192x512)
  float* dbc = xs + (size_t)4 * 1024 * 1024;      // 8192x48
  float* delta = dbc + (size_t)512 * 1024;        // 4M floats
  float* yb = delta + (size_t)4 * 1024 * 1024;    // 4M floats
  // Scan scratch overlays u (dead between in_proj and next rmsnorm)
  float* pf = u;                                  // 512K floats
  float* hf = pf + (size_t)524288;                // 512K floats
  float* hin = hf + (size_t)524288;               // 512K floats

  embed_kernel<<<2048, 256, 0, stream>>>(x, emb_w, emb_b, h);

  for (int l = 0; l < NLAYERS; l++) {
    rmsnorm_kernel<<<2048, 256, 0, stream>>>(h, norm_w + l * DMODEL, u);
    // in_proj: (8192,1024) = u(8192,256) @ W(1024,256)^T
    gemm_nt<0><<<dim3(1024 / 64, 8192 / 128), 256, 0, stream>>>(
        u, in_proj_w + (size_t)l * 2 * DINNER * DMODEL, xz, TOK, 2 * DINNER, DMODEL);
    conv_silu_kernel<<<4096, 256, 0, stream>>>(
        xz, conv_w + (size_t)l * DINNER * DCONV, conv_b + (size_t)l * DINNER, xs);
    // x_proj: (8192,48) = xs(8192,512) @ W(48,512)^T
    gemm_nt<0><<<dim3(1, 8192 / 128), 256, 0, stream>>>(
        xs, x_proj_w + (size_t)l * 48 * DINNER, dbc, TOK, 48, DINNER);
    dt_kernel<<<512, 256, 0, stream>>>(
        dbc, dt_proj_w + (size_t)l * DINNER * DTRANK, dt_proj_b + (size_t)l * DINNER, delta);
    // Chunked scan (u buffer is dead here; reused for carries)
    scan_phase1<<<2048, 256, 0, stream>>>(
        delta, dbc, xs, A_log + (size_t)l * DINNER * DSTATE, pf, hf);
    scan_phase2<<<128, 256, 0, stream>>>(pf, hf, hin);
    scan_phase3<<<2048, 256, 0, stream>>>(
        delta, dbc, xs, xz, A_log + (size_t)l * DINNER * DSTATE,
        Dp + (size_t)l * DINNER, hin, yb);
    // out_proj (+residual): h += yb(8192,512) @ W(256,512)^T
    gemm_nt<1><<<dim3(256 / 64, 8192 / 128), 256, 0, stream>>>(
        yb, out_proj_w + (size_t)l * DMODEL * DINNER, h, TOK, DMODEL, DINNER);
  }
}

// Round 3
// 714.090 us; speedup vs baseline: 4.8587x; 1.3377x over previous
//
#include <hip/hip_runtime.h>
#include <hip/hip_bf16.h>
#include <math.h>

// Problem constants
#define BB 4
#define WW 2048
#define TOK (BB * WW)        // 8192
#define DMODEL 256
#define DINNER 512
#define DSTATE 16
#define DTRANK 16
#define DCONV 4
#define NLAYERS 2
#define CHUNKS 16
#define CLEN (WW / CHUNKS)   // 128

// ---------------------------------------------------------------------------
// Embed: h[tok][d] = x[tok] * emb_w[d] + emb_b[d]
// ---------------------------------------------------------------------------
__global__ __launch_bounds__(256) void embed_kernel(
    const float* __restrict__ x, const float* __restrict__ ew,
    const float* __restrict__ eb, float* __restrict__ h) {
  int idx = blockIdx.x * 256 + threadIdx.x;     // TOK*64 threads, 4 d each
  int tok = idx >> 6;
  int d4 = (idx & 63) * 4;
  float xv = x[tok];
  float4 w = *(const float4*)&ew[d4];
  float4 b = *(const float4*)&eb[d4];
  float4 o;
  o.x = xv * w.x + b.x;
  o.y = xv * w.y + b.y;
  o.z = xv * w.z + b.z;
  o.w = xv * w.w + b.w;
  *(float4*)&h[(size_t)tok * DMODEL + d4] = o;
}

// ---------------------------------------------------------------------------
// RMSNorm: one wave per token (256 floats = 64 lanes x float4)
// ---------------------------------------------------------------------------
__global__ __launch_bounds__(256) void rmsnorm_kernel(
    const float* __restrict__ h, const float* __restrict__ w,
    float* __restrict__ u) {
  int wave = threadIdx.x >> 6;
  int lane = threadIdx.x & 63;
  int tok = blockIdx.x * 4 + wave;
  const float* hp = h + (size_t)tok * DMODEL;
  float4 v = *(const float4*)&hp[lane * 4];
  float ss = v.x * v.x + v.y * v.y + v.z * v.z + v.w * v.w;
#pragma unroll
  for (int off = 32; off; off >>= 1) ss += __shfl_xor(ss, off, 64);
  float rs = rsqrtf(ss * (1.0f / 256.0f) + 1e-5f);
  float4 wv = *(const float4*)&w[lane * 4];
  float4 o;
  o.x = v.x * rs * wv.x;
  o.y = v.y * rs * wv.y;
  o.z = v.z * rs * wv.z;
  o.w = v.w * rs * wv.w;
  *(float4*)&u[(size_t)tok * DMODEL + lane * 4] = o;
}

// ---------------------------------------------------------------------------
// SGEMM: C[M,N] = A[M,K] * B[N,K]^T (both row-major, K-contiguous dot)
// BM=128, BN=64, BK=32, 256 threads, 8x4 per thread.
// EPI==1: C += result (residual add).
// ---------------------------------------------------------------------------
template <int EPI>
__global__ __launch_bounds__(256) void gemm_nt(
    const float* __restrict__ A, const float* __restrict__ Bw,
    float* __restrict__ C, int M, int N, int K) {
  __shared__ float As[32][128];
  __shared__ float Bs[32][64];
  int tid = threadIdx.x;
  int m0 = blockIdx.y * 128;
  int n0 = blockIdx.x * 64;
  int tx = tid & 15;
  int ty = tid >> 4;
  float acc[8][4] = {};

  for (int k0 = 0; k0 < K; k0 += 32) {
    // Load A tile 128x32: 4 float4 per thread
    {
      int r = tid >> 3;            // 0..31
      int c = (tid & 7) * 4;       // 0..28
#pragma unroll
      for (int i = 0; i < 4; i++) {
        int row = r + i * 32;
        float4 v = *(const float4*)&A[(size_t)(m0 + row) * K + k0 + c];
        As[c + 0][row] = v.x;
        As[c + 1][row] = v.y;
        As[c + 2][row] = v.z;
        As[c + 3][row] = v.w;
      }
    }
    // Load B tile 64x32: 2 float4 per thread (mask rows >= N)
    {
      int rb = tid >> 2;           // 0..63
      int cb = (tid & 3) * 8;      // 0,8,16,24
#pragma unroll
      for (int i = 0; i < 2; i++) {
        int col = cb + i * 4;
        float4 v = make_float4(0.f, 0.f, 0.f, 0.f);
        if (n0 + rb < N) v = *(const float4*)&Bw[(size_t)(n0 + rb) * K + k0 + col];
        Bs[col + 0][rb] = v.x;
        Bs[col + 1][rb] = v.y;
        Bs[col + 2][rb] = v.z;
        Bs[col + 3][rb] = v.w;
      }
    }
    __syncthreads();
#pragma unroll
    for (int kk = 0; kk < 32; kk++) {
      float4 a0 = *(const float4*)&As[kk][ty * 8];
      float4 a1 = *(const float4*)&As[kk][ty * 8 + 4];
      float4 b = *(const float4*)&Bs[kk][tx * 4];
      float av[8] = {a0.x, a0.y, a0.z, a0.w, a1.x, a1.y, a1.z, a1.w};
      float bv[4] = {b.x, b.y, b.z, b.w};
#pragma unroll
      for (int i = 0; i < 8; i++) {
#pragma unroll
        for (int j = 0; j < 4; j++) acc[i][j] = fmaf(av[i], bv[j], acc[i][j]);
      }
    }
    __syncthreads();
  }

  int n = n0 + tx * 4;
  if (n < N) {
#pragma unroll
    for (int i = 0; i < 8; i++) {
      int m = m0 + ty * 8 + i;
      float* p = &C[(size_t)m * N + n];
      float4 v = {acc[i][0], acc[i][1], acc[i][2], acc[i][3]};
      if (EPI == 1) {
        float4 o = *(const float4*)p;
        v.x += o.x; v.y += o.y; v.z += o.z; v.w += o.w;
      }
      *(float4*)p = v;
    }
  }
}

// ---------------------------------------------------------------------------
// Causal depthwise conv (D_CONV=4) + SiLU.  xc = xz[:, :, 0:512].
// One thread per (tok, 4 channels).
// ---------------------------------------------------------------------------
__global__ __launch_bounds__(256) void conv_silu_kernel(
    const float* __restrict__ xz, const float* __restrict__ cw,
    const float* __restrict__ cb, float* __restrict__ xs) {
  int idx = blockIdx.x * 256 + threadIdx.x;     // TOK*128
  int tok = idx >> 7;
  int c4 = (idx & 127) * 4;
  int b = tok >> 11;
  int t = tok & (WW - 1);
  float wch[4][4];
#pragma unroll
  for (int c = 0; c < 4; c++) {
    float4 w = *(const float4*)&cw[(c4 + c) * DCONV];
    wch[c][0] = w.x; wch[c][1] = w.y; wch[c][2] = w.z; wch[c][3] = w.w;
  }
  float4 bias = *(const float4*)&cb[c4];
  float acc[4] = {bias.x, bias.y, bias.z, bias.w};
#pragma unroll
  for (int k = 0; k < 4; k++) {
    int tt = t - 3 + k;
    if (tt >= 0) {
      float4 xv = *(const float4*)&xz[((size_t)(b * WW + tt)) * (2 * DINNER) + c4];
      acc[0] = fmaf(xv.x, wch[0][k], acc[0]);
      acc[1] = fmaf(xv.y, wch[1][k], acc[1]);
      acc[2] = fmaf(xv.z, wch[2][k], acc[2]);
      acc[3] = fmaf(xv.w, wch[3][k], acc[3]);
    }
  }
  float4 o;
  o.x = acc[0] / (1.f + __expf(-acc[0]));
  o.y = acc[1] / (1.f + __expf(-acc[1]));
  o.z = acc[2] / (1.f + __expf(-acc[2]));
  o.w = acc[3] / (1.f + __expf(-acc[3]));
  *(float4*)&xs[(size_t)tok * DINNER + c4] = o;
}

// ---------------------------------------------------------------------------
// dt projection + softplus: delta[m][n] = softplus(dbc[m][0:16] . dtw[n][:] + dtb[n])
// Block handles 16 tokens x 512 n.  dtw staged in LDS (padded rows).
// ---------------------------------------------------------------------------
__global__ __launch_bounds__(256) void dt_kernel(
    const float* __restrict__ dbc, const float* __restrict__ dtw,
    const float* __restrict__ dtb, float* __restrict__ delta) {
  __shared__ float ws[512][17];   // +1 pad breaks stride-16 bank aliasing
  __shared__ float ds[16][16];
  int tid = threadIdx.x;
  int tok0 = blockIdx.x * 16;
#pragma unroll
  for (int i = 0; i < 2; i++) {
    int r = tid * 2 + i;
#pragma unroll
    for (int j = 0; j < 4; j++) {
      float4 v = *(const float4*)&dtw[r * 16 + j * 4];
      ws[r][j * 4 + 0] = v.x;
      ws[r][j * 4 + 1] = v.y;
      ws[r][j * 4 + 2] = v.z;
      ws[r][j * 4 + 3] = v.w;
    }
  }
  if (tid < 64) {
    int m = tid >> 2, j = (tid & 3) * 4;
    *(float4*)&ds[m][j] = *(const float4*)&dbc[(size_t)(tok0 + m) * 48 + j];
  }
  __syncthreads();
#pragma unroll
  for (int pass = 0; pass < 2; pass++) {
    int n = tid + pass * 256;
    float w[16];
#pragma unroll
    for (int r = 0; r < 16; r++) w[r] = ws[n][r];
    float bias = dtb[n];
#pragma unroll
    for (int m = 0; m < 16; m++) {
      float s = bias;
#pragma unroll
      for (int r = 0; r < 16; r++) s = fmaf(ds[m][r], w[r], s);
      float sp = (s > 20.f) ? s : log1pf(expf(s));
      delta[(size_t)(tok0 + m) * DINNER + n] = sp;
    }
  }
}

// ---------------------------------------------------------------------------
// Chunked selective scan, d-coalesced layout.
// Thread owns (b, d, chunk) with 4 states in registers (sg = tid&3).
// A wave's lanes cover 16 consecutive d -> delta/u/z loads are contiguous
// 64B segments; B/C are broadcast float4 from dbc; the C-dot is a 2-level
// shfl_xor across the sg group.  Scratch layout: [g=b*512+d][c][s].
// ---------------------------------------------------------------------------
__global__ __launch_bounds__(256) void scan_phase1(
    const float* __restrict__ delta, const float* __restrict__ dbc,
    const float* __restrict__ xs, const float* __restrict__ A_log,
    float* __restrict__ Pfin, float* __restrict__ Hfin) {
  int blk = blockIdx.x;            // ((b*CHUNKS + c) * 8 + dblk)
  int dblk = blk & 7;
  int bc = blk >> 3;
  int c = bc & (CHUNKS - 1);
  int b = bc >> 4;
  int tid = threadIdx.x;
  int sg = tid & 3;
  int dl = tid >> 2;               // 0..63
  int d = dblk * 64 + dl;
  float4 Al = *(const float4*)&A_log[d * DSTATE + sg * 4];
  float A0 = -__expf(Al.x), A1 = -__expf(Al.y);
  float A2 = -__expf(Al.z), A3 = -__expf(Al.w);
  int t0 = c * CLEN;
  const float* dp_ = delta + ((size_t)(b * WW + t0)) * DINNER + d;
  const float* up_ = xs + ((size_t)(b * WW + t0)) * DINNER + d;
  const float* bcp = dbc + ((size_t)(b * WW + t0)) * 48 + DTRANK + sg * 4;
  float h0 = 0.f, h1 = 0.f, h2 = 0.f, h3 = 0.f;
  float P0 = 1.f, P1 = 1.f, P2 = 1.f, P3 = 1.f;
#pragma unroll 4
  for (int t = 0; t < CLEN; t++) {
    float dv = dp_[(size_t)t * DINNER];
    float uv = up_[(size_t)t * DINNER];
    float4 Bv = *(const float4*)&bcp[t * 48];
    float du = dv * uv;
    float e0 = __expf(dv * A0); P0 *= e0; h0 = fmaf(e0, h0, du * Bv.x);
    float e1 = __expf(dv * A1); P1 *= e1; h1 = fmaf(e1, h1, du * Bv.y);
    float e2 = __expf(dv * A2); P2 *= e2; h2 = fmaf(e2, h2, du * Bv.z);
    float e3 = __expf(dv * A3); P3 *= e3; h3 = fmaf(e3, h3, du * Bv.w);
  }
  size_t o = ((size_t)(b * 512 + d) * CHUNKS + c) * DSTATE + sg * 4;
  float4 Pv = {P0, P1, P2, P3};
  float4 Hv = {h0, h1, h2, h3};
  *(float4*)&Pfin[o] = Pv;
  *(float4*)&Hfin[o] = Hv;
}

__global__ __launch_bounds__(256) void scan_phase2(
    const float* __restrict__ Pfin, const float* __restrict__ Hfin,
    float* __restrict__ Hin) {
  int idx = blockIdx.x * 256 + threadIdx.x;  // 32768 = g*16+s
  int s = idx & 15;
  int g = idx >> 4;
  float h = 0.f;
#pragma unroll
  for (int c = 0; c < CHUNKS; c++) {
    size_t o = ((size_t)g * CHUNKS + c) * DSTATE + s;
    Hin[o] = h;
    h = fmaf(Pfin[o], h, Hfin[o]);
  }
}

__global__ __launch_bounds__(256) void scan_phase3(
    const float* __restrict__ delta, const float* __restrict__ dbc,
    const float* __restrict__ xs, const float* __restrict__ xz,
    const float* __restrict__ A_log, const float* __restrict__ Dp,
    const float* __restrict__ Hin, float* __restrict__ y) {
  int blk = blockIdx.x;
  int dblk = blk & 7;
  int bc = blk >> 3;
  int c = bc & (CHUNKS - 1);
  int b = bc >> 4;
  int tid = threadIdx.x;
  int sg = tid & 3;
  int dl = tid >> 2;
  int d = dblk * 64 + dl;
  float4 Al = *(const float4*)&A_log[d * DSTATE + sg * 4];
  float A0 = -__expf(Al.x), A1 = -__expf(Al.y);
  float A2 = -__expf(Al.z), A3 = -__expf(Al.w);
  float Dv = Dp[d];
  int t0 = c * CLEN;
  const float* dp_ = delta + ((size_t)(b * WW + t0)) * DINNER + d;
  const float* up_ = xs + ((size_t)(b * WW + t0)) * DINNER + d;
  const float* bcp = dbc + ((size_t)(b * WW + t0)) * 48 + DTRANK + sg * 4;
  const float* zb = xz + ((size_t)(b * WW + t0)) * (2 * DINNER) + DINNER + d;
  float* yp = y + ((size_t)(b * WW + t0)) * DINNER + d;
  size_t o = ((size_t)(b * 512 + d) * CHUNKS + c) * DSTATE + sg * 4;
  float4 Hv = *(const float4*)&Hin[o];
  float h0 = Hv.x, h1 = Hv.y, h2 = Hv.z, h3 = Hv.w;
#pragma unroll 4
  for (int t = 0; t < CLEN; t++) {
    float dv = dp_[(size_t)t * DINNER];
    float uv = up_[(size_t)t * DINNER];
    float zv = zb[(size_t)t * (2 * DINNER)];
    float4 Bv = *(const float4*)&bcp[t * 48];
    float4 Cv = *(const float4*)&bcp[t * 48 + DSTATE];
    float du = dv * uv;
    float e0 = __expf(dv * A0); h0 = fmaf(e0, h0, du * Bv.x);
    float e1 = __expf(dv * A1); h1 = fmaf(e1, h1, du * Bv.y);
    float e2 = __expf(dv * A2); h2 = fmaf(e2, h2, du * Bv.z);
    float e3 = __expf(dv * A3); h3 = fmaf(e3, h3, du * Bv.w);
    float p = h0 * Cv.x + h1 * Cv.y + h2 * Cv.z + h3 * Cv.w;
    p += __shfl_xor(p, 1, 64);
    p += __shfl_xor(p, 2, 64);
    if (sg == 0) {
      float yv = fmaf(uv, Dv, p);
      yv *= zv / (1.f + __expf(-zv));
      yp[(size_t)t * DINNER] = yv;
    }
  }
}

// ---------------------------------------------------------------------------
extern "C" void kernel_launch(void* const* d_in, const int* in_sizes, int n_in,
                              void* d_out, int out_size, void* d_ws, size_t ws_size,
                              hipStream_t stream) {
  const float* x = (const float*)d_in[0];
  const float* emb_w = (const float*)d_in[1];
  const float* emb_b = (const float*)d_in[2];
  const float* in_proj_w = (const float*)d_in[3];
  const float* conv_w = (const float*)d_in[4];
  const float* conv_b = (const float*)d_in[5];
  const float* x_proj_w = (const float*)d_in[6];
  const float* dt_proj_w = (const float*)d_in[7];
  const float* dt_proj_b = (const float*)d_in[8];
  const float* A_log = (const float*)d_in[9];
  const float* Dp = (const float*)d_in[10];
  const float* out_proj_w = (const float*)d_in[11];
  const float* norm_w = (const float*)d_in[12];

  float* h = (float*)d_out;                       // (8192, 256)
  float* ws = (float*)d_ws;
  float* u = ws;                                  // 2M floats (free during scan)
  float* xz = u + (size_t)2 * 1024 * 1024;        // 8M floats (8192x1024)
  float* xs = xz + (size_t)8 * 1024 * 1024;       // 4M floats (8192x512)
  float* dbc = xs + (size_t)4 * 1024 * 1024;      // 8192x48
  float* delta = dbc + (size_t)512 * 1024;        // 4M floats
  float* yb = delta + (size_t)4 * 1024 * 1024;    // 4M floats
  // Scan scratch overlays u (dead between in_proj and next rmsnorm):
  // 2048 g x 16 c x 16 s = 512K floats each, 1.5M total < u's 2M.
  float* pf = u;                                  // 512K floats
  float* hf = pf + (size_t)524288;                // 512K floats
  float* hin = hf + (size_t)524288;               // 512K floats

  embed_kernel<<<2048, 256, 0, stream>>>(x, emb_w, emb_b, h);

  for (int l = 0; l < NLAYERS; l++) {
    rmsnorm_kernel<<<2048, 256, 0, stream>>>(h, norm_w + l * DMODEL, u);
    // in_proj: (8192,1024) = u(8192,256) @ W(1024,256)^T
    gemm_nt<0><<<dim3(1024 / 64, 8192 / 128), 256, 0, stream>>>(
        u, in_proj_w + (size_t)l * 2 * DINNER * DMODEL, xz, TOK, 2 * DINNER, DMODEL);
    conv_silu_kernel<<<4096, 256, 0, stream>>>(
        xz, conv_w + (size_t)l * DINNER * DCONV, conv_b + (size_t)l * DINNER, xs);
    // x_proj: (8192,48) = xs(8192,512) @ W(48,512)^T
    gemm_nt<0><<<dim3(1, 8192 / 128), 256, 0, stream>>>(
        xs, x_proj_w + (size_t)l * 48 * DINNER, dbc, TOK, 48, DINNER);
    dt_kernel<<<512, 256, 0, stream>>>(
        dbc, dt_proj_w + (size_t)l * DINNER * DTRANK, dt_proj_b + (size_t)l * DINNER, delta);
    // Chunked scan: 512 blocks = (b*16 + c)*8 + dblk
    scan_phase1<<<BB * CHUNKS * 8, 256, 0, stream>>>(
        delta, dbc, xs, A_log + (size_t)l * DINNER * DSTATE, pf, hf);
    scan_phase2<<<128, 256, 0, stream>>>(pf, hf, hin);
    scan_phase3<<<BB * CHUNKS * 8, 256, 0, stream>>>(
        delta, dbc, xs, xz, A_log + (size_t)l * DINNER * DSTATE,
        Dp + (size_t)l * DINNER, hin, yb);
    // out_proj (+residual): h += yb(8192,512) @ W(256,512)^T
    gemm_nt<1><<<dim3(256 / 64, 8192 / 128), 256, 0, stream>>>(
        yb, out_proj_w + (size_t)l * DMODEL * DINNER, h, TOK, DMODEL, DINNER);
  }
}

// Round 4
// 496.285 us; speedup vs baseline: 6.9910x; 1.4389x over previous
//
#include <hip/hip_runtime.h>
#include <hip/hip_bf16.h>
#include <math.h>

// Problem constants
#define BB 4
#define WW 2048
#define TOK (BB * WW)        // 8192
#define DMODEL 256
#define DINNER 512
#define DSTATE 16
#define DTRANK 16
#define DCONV 4
#define NLAYERS 2
#define CHUNKS 32
#define CLEN (WW / CHUNKS)   // 64

typedef __attribute__((ext_vector_type(8))) short short8;
typedef __attribute__((ext_vector_type(4))) float floatx4;

static __device__ __forceinline__ unsigned short f2bf(float f) {
  __hip_bfloat16 b = __float2bfloat16(f);
  return *(unsigned short*)&b;
}

static __device__ __forceinline__ void load_lds16(const void* g, void* l) {
  __builtin_amdgcn_global_load_lds(
      (const __attribute__((address_space(1))) unsigned int*)g,
      (__attribute__((address_space(3))) unsigned int*)l, 16, 0, 0);
}

// ---------------------------------------------------------------------------
// Embed: h[tok][d] = x[tok] * emb_w[d] + emb_b[d]
// ---------------------------------------------------------------------------
__global__ __launch_bounds__(256) void embed_kernel(
    const float* __restrict__ x, const float* __restrict__ ew,
    const float* __restrict__ eb, float* __restrict__ h) {
  int idx = blockIdx.x * 256 + threadIdx.x;
  int tok = idx >> 6;
  int d4 = (idx & 63) * 4;
  float xv = x[tok];
  float4 w = *(const float4*)&ew[d4];
  float4 b = *(const float4*)&eb[d4];
  float4 o;
  o.x = xv * w.x + b.x;
  o.y = xv * w.y + b.y;
  o.z = xv * w.z + b.z;
  o.w = xv * w.w + b.w;
  *(float4*)&h[(size_t)tok * DMODEL + d4] = o;
}

// ---------------------------------------------------------------------------
// RMSNorm: one wave per token; output cast to bf16 (in_proj MFMA A-operand)
// ---------------------------------------------------------------------------
__global__ __launch_bounds__(256) void rmsnorm_kernel(
    const float* __restrict__ h, const float* __restrict__ w,
    unsigned short* __restrict__ ub) {
  int wave = threadIdx.x >> 6;
  int lane = threadIdx.x & 63;
  int tok = blockIdx.x * 4 + wave;
  const float* hp = h + (size_t)tok * DMODEL;
  float4 v = *(const float4*)&hp[lane * 4];
  float ss = v.x * v.x + v.y * v.y + v.z * v.z + v.w * v.w;
#pragma unroll
  for (int off = 32; off; off >>= 1) ss += __shfl_xor(ss, off, 64);
  float rs = rsqrtf(ss * (1.0f / 256.0f) + 1e-5f);
  float4 wv = *(const float4*)&w[lane * 4];
  ushort4 o;
  o.x = f2bf(v.x * rs * wv.x);
  o.y = f2bf(v.y * rs * wv.y);
  o.z = f2bf(v.z * rs * wv.z);
  o.w = f2bf(v.w * rs * wv.w);
  *(ushort4*)&ub[(size_t)tok * DMODEL + lane * 4] = o;
}

// ---------------------------------------------------------------------------
// fp32 -> bf16 cast (weights), 4 elements/thread
// ---------------------------------------------------------------------------
__global__ __launch_bounds__(256) void cast_bf16_kernel(
    const float* __restrict__ src, unsigned short* __restrict__ dst) {
  int i = (blockIdx.x * 256 + threadIdx.x) * 4;
  float4 v = *(const float4*)&src[i];
  ushort4 o = {f2bf(v.x), f2bf(v.y), f2bf(v.z), f2bf(v.w)};
  *(ushort4*)&dst[i] = o;
}

// ---------------------------------------------------------------------------
// bf16 MFMA GEMM: C[M,N] (+)= A[M,K] * B[N,K]^T.  A,B bf16 row-major
// (K-contiguous), C fp32.  128x128 tile, BK=32, 4 waves, wave tile 64x64 =
// 4x4 mfma_f32_16x16x32_bf16.  Staging via global_load_lds width 16
// (wave-uniform LDS base + lane*16: LDS tile must be unpadded row-major).
// Requires M%128==0, N%128==0, K%32==0.
// ---------------------------------------------------------------------------
template <int EPI>
__global__ __launch_bounds__(256) void gemm_bf16(
    const unsigned short* __restrict__ A, const unsigned short* __restrict__ Bw,
    float* __restrict__ C, int M, int N, int K) {
  __shared__ unsigned short As[128 * 32];   // row-major 128 x 32, 64 B rows
  __shared__ unsigned short Bs[128 * 32];
  int tid = threadIdx.x;
  int wave = tid >> 6;
  int lane = tid & 63;
  int wm = (wave & 1) * 64;
  int wn = (wave >> 1) * 64;
  int m0 = blockIdx.y * 128;
  int n0 = blockIdx.x * 128;
  int mlane = lane & 15;
  int quad = lane >> 4;
  floatx4 acc[4][4] = {};

  for (int k0 = 0; k0 < K; k0 += 32) {
    // Stage A and B tiles: 8 KB each; per wave-instruction 1024 B (16 rows)
#pragma unroll
    for (int i = 0; i < 2; i++) {
      int off = i * 4096 + wave * 1024 + lane * 16;  // byte offset in tile
      int row = off >> 6;
      int col = off & 63;
      load_lds16((const char*)A + ((size_t)(m0 + row) * K + k0) * 2 + col,
                 (char*)As + i * 4096 + wave * 1024);
    }
#pragma unroll
    for (int i = 0; i < 2; i++) {
      int off = i * 4096 + wave * 1024 + lane * 16;
      int row = off >> 6;
      int col = off & 63;
      load_lds16((const char*)Bw + ((size_t)(n0 + row) * K + k0) * 2 + col,
                 (char*)Bs + i * 4096 + wave * 1024);
    }
    __syncthreads();
    short8 af[4], bf[4];
#pragma unroll
    for (int i = 0; i < 4; i++)
      af[i] = *(const short8*)((const char*)As + (wm + i * 16 + mlane) * 64 + quad * 16);
#pragma unroll
    for (int j = 0; j < 4; j++)
      bf[j] = *(const short8*)((const char*)Bs + (wn + j * 16 + mlane) * 64 + quad * 16);
#pragma unroll
    for (int i = 0; i < 4; i++)
#pragma unroll
      for (int j = 0; j < 4; j++)
        acc[i][j] = __builtin_amdgcn_mfma_f32_16x16x32_bf16(af[i], bf[j], acc[i][j], 0, 0, 0);
    __syncthreads();
  }

  // Epilogue: D row = m = quad*4 + reg, col = n = lane&15 (m89-verified)
#pragma unroll
  for (int i = 0; i < 4; i++) {
#pragma unroll
    for (int j = 0; j < 4; j++) {
      int n = n0 + wn + j * 16 + mlane;
#pragma unroll
      for (int r = 0; r < 4; r++) {
        int m = m0 + wm + i * 16 + quad * 4 + r;
        float* p = &C[(size_t)m * N + n];
        float v = acc[i][j][r];
        if (EPI == 1) v += *p;
        *p = v;
      }
    }
  }
}

// ---------------------------------------------------------------------------
// fp32 SGEMM (kept for x_proj, N=48): C[M,N] = A[M,K]*B[N,K]^T
// ---------------------------------------------------------------------------
template <int EPI>
__global__ __launch_bounds__(256) void gemm_nt(
    const float* __restrict__ A, const float* __restrict__ Bw,
    float* __restrict__ C, int M, int N, int K) {
  __shared__ float As[32][128];
  __shared__ float Bs[32][64];
  int tid = threadIdx.x;
  int m0 = blockIdx.y * 128;
  int n0 = blockIdx.x * 64;
  int tx = tid & 15;
  int ty = tid >> 4;
  float acc[8][4] = {};

  for (int k0 = 0; k0 < K; k0 += 32) {
    {
      int r = tid >> 3;
      int c = (tid & 7) * 4;
#pragma unroll
      for (int i = 0; i < 4; i++) {
        int row = r + i * 32;
        float4 v = *(const float4*)&A[(size_t)(m0 + row) * K + k0 + c];
        As[c + 0][row] = v.x;
        As[c + 1][row] = v.y;
        As[c + 2][row] = v.z;
        As[c + 3][row] = v.w;
      }
    }
    {
      int rb = tid >> 2;
      int cb = (tid & 3) * 8;
#pragma unroll
      for (int i = 0; i < 2; i++) {
        int col = cb + i * 4;
        float4 v = make_float4(0.f, 0.f, 0.f, 0.f);
        if (n0 + rb < N) v = *(const float4*)&Bw[(size_t)(n0 + rb) * K + k0 + col];
        Bs[col + 0][rb] = v.x;
        Bs[col + 1][rb] = v.y;
        Bs[col + 2][rb] = v.z;
        Bs[col + 3][rb] = v.w;
      }
    }
    __syncthreads();
#pragma unroll
    for (int kk = 0; kk < 32; kk++) {
      float4 a0 = *(const float4*)&As[kk][ty * 8];
      float4 a1 = *(const float4*)&As[kk][ty * 8 + 4];
      float4 b = *(const float4*)&Bs[kk][tx * 4];
      float av[8] = {a0.x, a0.y, a0.z, a0.w, a1.x, a1.y, a1.z, a1.w};
      float bv[4] = {b.x, b.y, b.z, b.w};
#pragma unroll
      for (int i = 0; i < 8; i++)
#pragma unroll
        for (int j = 0; j < 4; j++) acc[i][j] = fmaf(av[i], bv[j], acc[i][j]);
    }
    __syncthreads();
  }

  int n = n0 + tx * 4;
  if (n < N) {
#pragma unroll
    for (int i = 0; i < 8; i++) {
      int m = m0 + ty * 8 + i;
      float* p = &C[(size_t)m * N + n];
      float4 v = {acc[i][0], acc[i][1], acc[i][2], acc[i][3]};
      if (EPI == 1) {
        float4 o = *(const float4*)p;
        v.x += o.x; v.y += o.y; v.z += o.z; v.w += o.w;
      }
      *(float4*)p = v;
    }
  }
}

// ---------------------------------------------------------------------------
// Causal depthwise conv (D_CONV=4) + SiLU.
// ---------------------------------------------------------------------------
__global__ __launch_bounds__(256) void conv_silu_kernel(
    const float* __restrict__ xz, const float* __restrict__ cw,
    const float* __restrict__ cb, float* __restrict__ xs) {
  int idx = blockIdx.x * 256 + threadIdx.x;
  int tok = idx >> 7;
  int c4 = (idx & 127) * 4;
  int b = tok >> 11;
  int t = tok & (WW - 1);
  float wch[4][4];
#pragma unroll
  for (int c = 0; c < 4; c++) {
    float4 w = *(const float4*)&cw[(c4 + c) * DCONV];
    wch[c][0] = w.x; wch[c][1] = w.y; wch[c][2] = w.z; wch[c][3] = w.w;
  }
  float4 bias = *(const float4*)&cb[c4];
  float acc[4] = {bias.x, bias.y, bias.z, bias.w};
#pragma unroll
  for (int k = 0; k < 4; k++) {
    int tt = t - 3 + k;
    if (tt >= 0) {
      float4 xv = *(const float4*)&xz[((size_t)(b * WW + tt)) * (2 * DINNER) + c4];
      acc[0] = fmaf(xv.x, wch[0][k], acc[0]);
      acc[1] = fmaf(xv.y, wch[1][k], acc[1]);
      acc[2] = fmaf(xv.z, wch[2][k], acc[2]);
      acc[3] = fmaf(xv.w, wch[3][k], acc[3]);
    }
  }
  float4 o;
  o.x = acc[0] / (1.f + __expf(-acc[0]));
  o.y = acc[1] / (1.f + __expf(-acc[1]));
  o.z = acc[2] / (1.f + __expf(-acc[2]));
  o.w = acc[3] / (1.f + __expf(-acc[3]));
  *(float4*)&xs[(size_t)tok * DINNER + c4] = o;
}

// ---------------------------------------------------------------------------
// dt projection + softplus
// ---------------------------------------------------------------------------
__global__ __launch_bounds__(256) void dt_kernel(
    const float* __restrict__ dbc, const float* __restrict__ dtw,
    const float* __restrict__ dtb, float* __restrict__ delta) {
  __shared__ float ws[512][17];
  __shared__ float ds[16][16];
  int tid = threadIdx.x;
  int tok0 = blockIdx.x * 16;
#pragma unroll
  for (int i = 0; i < 2; i++) {
    int r = tid * 2 + i;
#pragma unroll
    for (int j = 0; j < 4; j++) {
      float4 v = *(const float4*)&dtw[r * 16 + j * 4];
      ws[r][j * 4 + 0] = v.x;
      ws[r][j * 4 + 1] = v.y;
      ws[r][j * 4 + 2] = v.z;
      ws[r][j * 4 + 3] = v.w;
    }
  }
  if (tid < 64) {
    int m = tid >> 2, j = (tid & 3) * 4;
    *(float4*)&ds[m][j] = *(const float4*)&dbc[(size_t)(tok0 + m) * 48 + j];
  }
  __syncthreads();
#pragma unroll
  for (int pass = 0; pass < 2; pass++) {
    int n = tid + pass * 256;
    float w[16];
#pragma unroll
    for (int r = 0; r < 16; r++) w[r] = ws[n][r];
    float bias = dtb[n];
#pragma unroll
    for (int m = 0; m < 16; m++) {
      float s = bias;
#pragma unroll
      for (int r = 0; r < 16; r++) s = fmaf(ds[m][r], w[r], s);
      float sp = (s > 20.f) ? s : log1pf(expf(s));
      delta[(size_t)(tok0 + m) * DINNER + n] = sp;
    }
  }
}

// ---------------------------------------------------------------------------
// Chunked selective scan, d-coalesced.  CHUNKS=32 -> 4096 waves (4/SIMD).
// ---------------------------------------------------------------------------
__global__ __launch_bounds__(256) void scan_phase1(
    const float* __restrict__ delta, const float* __restrict__ dbc,
    const float* __restrict__ xs, const float* __restrict__ A_log,
    float* __restrict__ Pfin, float* __restrict__ Hfin) {
  int blk = blockIdx.x;            // ((b*CHUNKS + c) * 8 + dblk)
  int dblk = blk & 7;
  int bc = blk >> 3;
  int c = bc % CHUNKS;
  int b = bc / CHUNKS;
  int tid = threadIdx.x;
  int sg = tid & 3;
  int dl = tid >> 2;
  int d = dblk * 64 + dl;
  float4 Al = *(const float4*)&A_log[d * DSTATE + sg * 4];
  float A0 = -__expf(Al.x), A1 = -__expf(Al.y);
  float A2 = -__expf(Al.z), A3 = -__expf(Al.w);
  int t0 = c * CLEN;
  const float* dp_ = delta + ((size_t)(b * WW + t0)) * DINNER + d;
  const float* up_ = xs + ((size_t)(b * WW + t0)) * DINNER + d;
  const float* bcp = dbc + ((size_t)(b * WW + t0)) * 48 + DTRANK + sg * 4;
  float h0 = 0.f, h1 = 0.f, h2 = 0.f, h3 = 0.f;
  float P0 = 1.f, P1 = 1.f, P2 = 1.f, P3 = 1.f;
#pragma unroll 4
  for (int t = 0; t < CLEN; t++) {
    float dv = dp_[(size_t)t * DINNER];
    float uv = up_[(size_t)t * DINNER];
    float4 Bv = *(const float4*)&bcp[t * 48];
    float du = dv * uv;
    float e0 = __expf(dv * A0); P0 *= e0; h0 = fmaf(e0, h0, du * Bv.x);
    float e1 = __expf(dv * A1); P1 *= e1; h1 = fmaf(e1, h1, du * Bv.y);
    float e2 = __expf(dv * A2); P2 *= e2; h2 = fmaf(e2, h2, du * Bv.z);
    float e3 = __expf(dv * A3); P3 *= e3; h3 = fmaf(e3, h3, du * Bv.w);
  }
  size_t o = ((size_t)(b * 512 + d) * CHUNKS + c) * DSTATE + sg * 4;
  float4 Pv = {P0, P1, P2, P3};
  float4 Hv = {h0, h1, h2, h3};
  *(float4*)&Pfin[o] = Pv;
  *(float4*)&Hfin[o] = Hv;
}

// In-place: Hin overwrites Pfin.
__global__ __launch_bounds__(256) void scan_phase2(
    float* __restrict__ Pfin, const float* __restrict__ Hfin) {
  int idx = blockIdx.x * 256 + threadIdx.x;  // 32768 = g*16+s
  int s = idx & 15;
  int g = idx >> 4;
  float h = 0.f;
#pragma unroll
  for (int c = 0; c < CHUNKS; c++) {
    size_t o = ((size_t)g * CHUNKS + c) * DSTATE + s;
    float P = Pfin[o];
    float f = Hfin[o];
    Pfin[o] = h;             // carry-in for chunk c
    h = fmaf(P, h, f);
  }
}

__global__ __launch_bounds__(256) void scan_phase3(
    const float* __restrict__ delta, const float* __restrict__ dbc,
    const float* __restrict__ xs, const float* __restrict__ xz,
    const float* __restrict__ A_log, const float* __restrict__ Dp,
    const float* __restrict__ Hin, unsigned short* __restrict__ yb) {
  int blk = blockIdx.x;
  int dblk = blk & 7;
  int bc = blk >> 3;
  int c = bc % CHUNKS;
  int b = bc / CHUNKS;
  int tid = threadIdx.x;
  int sg = tid & 3;
  int dl = tid >> 2;
  int d = dblk * 64 + dl;
  float4 Al = *(const float4*)&A_log[d * DSTATE + sg * 4];
  float A0 = -__expf(Al.x), A1 = -__expf(Al.y);
  float A2 = -__expf(Al.z), A3 = -__expf(Al.w);
  float Dv = Dp[d];
  int t0 = c * CLEN;
  const float* dp_ = delta + ((size_t)(b * WW + t0)) * DINNER + d;
  const float* up_ = xs + ((size_t)(b * WW + t0)) * DINNER + d;
  const float* bcp = dbc + ((size_t)(b * WW + t0)) * 48 + DTRANK + sg * 4;
  const float* zb = xz + ((size_t)(b * WW + t0)) * (2 * DINNER) + DINNER + d;
  unsigned short* yp = yb + ((size_t)(b * WW + t0)) * DINNER + d;
  size_t o = ((size_t)(b * 512 + d) * CHUNKS + c) * DSTATE + sg * 4;
  float4 Hv = *(const float4*)&Hin[o];
  float h0 = Hv.x, h1 = Hv.y, h2 = Hv.z, h3 = Hv.w;
#pragma unroll 4
  for (int t = 0; t < CLEN; t++) {
    float dv = dp_[(size_t)t * DINNER];
    float uv = up_[(size_t)t * DINNER];
    float zv = zb[(size_t)t * (2 * DINNER)];
    float4 Bv = *(const float4*)&bcp[t * 48];
    float4 Cv = *(const float4*)&bcp[t * 48 + DSTATE];
    float du = dv * uv;
    float e0 = __expf(dv * A0); h0 = fmaf(e0, h0, du * Bv.x);
    float e1 = __expf(dv * A1); h1 = fmaf(e1, h1, du * Bv.y);
    float e2 = __expf(dv * A2); h2 = fmaf(e2, h2, du * Bv.z);
    float e3 = __expf(dv * A3); h3 = fmaf(e3, h3, du * Bv.w);
    float p = h0 * Cv.x + h1 * Cv.y + h2 * Cv.z + h3 * Cv.w;
    p += __shfl_xor(p, 1, 64);
    p += __shfl_xor(p, 2, 64);
    if (sg == 0) {
      float yv = fmaf(uv, Dv, p);
      yv *= zv / (1.f + __expf(-zv));
      yp[(size_t)t * DINNER] = f2bf(yv);
    }
  }
}

// ---------------------------------------------------------------------------
extern "C" void kernel_launch(void* const* d_in, const int* in_sizes, int n_in,
                              void* d_out, int out_size, void* d_ws, size_t ws_size,
                              hipStream_t stream) {
  const float* x = (const float*)d_in[0];
  const float* emb_w = (const float*)d_in[1];
  const float* emb_b = (const float*)d_in[2];
  const float* in_proj_w = (const float*)d_in[3];
  const float* conv_w = (const float*)d_in[4];
  const float* conv_b = (const float*)d_in[5];
  const float* x_proj_w = (const float*)d_in[6];
  const float* dt_proj_w = (const float*)d_in[7];
  const float* dt_proj_b = (const float*)d_in[8];
  const float* A_log = (const float*)d_in[9];
  const float* Dp = (const float*)d_in[10];
  const float* out_proj_w = (const float*)d_in[11];
  const float* norm_w = (const float*)d_in[12];

  float* h = (float*)d_out;                       // (8192, 256)
  float* ws = (float*)d_ws;
  // Region map (floats from ws base), footprint identical to round 2 (22.5M):
  //   [0,2M)      : u_bf16 (1M fl-eq) -> later Pfin(1M)+Hfin(1M); Hin=Pfin
  //   [2M,10M)    : xz (8192x1024 fp32)
  //   [10M,14M)   : xs (8192x512 fp32)
  //   [14M,14.5M) : dbc (8192x48 fp32)
  //   [14.5M,18.5M): delta
  //   [18.5M,22.5M): yb_bf16 (2M fl-eq) | wA_bf16 | wO_bf16
  const size_t M1 = 1024 * 1024;
  unsigned short* ub = (unsigned short*)ws;
  float* pf = ws;
  float* hf = ws + M1;
  float* xz = ws + 2 * M1;
  float* xs = ws + 10 * M1;
  float* dbc = ws + 14 * M1;
  float* delta = ws + 14 * M1 + 524288;
  unsigned short* ybb = (unsigned short*)(ws + 14 * M1 + 524288 + 4 * M1);
  unsigned short* wA = (unsigned short*)(ws + 20 * M1 + 524288 + 524288);
  unsigned short* wO = wA + 2 * DINNER * DMODEL;   // 262144 bf16 later

  embed_kernel<<<2048, 256, 0, stream>>>(x, emb_w, emb_b, h);

  for (int l = 0; l < NLAYERS; l++) {
    // Weight casts (tiny): in_proj 1024x256, out_proj 256x512
    cast_bf16_kernel<<<256, 256, 0, stream>>>(
        in_proj_w + (size_t)l * 2 * DINNER * DMODEL, wA);
    cast_bf16_kernel<<<128, 256, 0, stream>>>(
        out_proj_w + (size_t)l * DMODEL * DINNER, wO);

    rmsnorm_kernel<<<2048, 256, 0, stream>>>(h, norm_w + l * DMODEL, ub);
    // in_proj: (8192,1024) = u_bf16 @ wA^T  [MFMA]
    gemm_bf16<0><<<dim3(1024 / 128, 8192 / 128), 256, 0, stream>>>(
        ub, wA, xz, TOK, 2 * DINNER, DMODEL);
    conv_silu_kernel<<<4096, 256, 0, stream>>>(
        xz, conv_w + (size_t)l * DINNER * DCONV, conv_b + (size_t)l * DINNER, xs);
    // x_proj: (8192,48) = xs @ W^T  [fp32, error-sensitive path]
    gemm_nt<0><<<dim3(1, 8192 / 128), 256, 0, stream>>>(
        xs, x_proj_w + (size_t)l * 48 * DINNER, dbc, TOK, 48, DINNER);
    dt_kernel<<<512, 256, 0, stream>>>(
        dbc, dt_proj_w + (size_t)l * DINNER * DTRANK, dt_proj_b + (size_t)l * DINNER, delta);
    // Chunked scan: 1024 blocks = (b*CHUNKS + c)*8 + dblk
    scan_phase1<<<BB * CHUNKS * 8, 256, 0, stream>>>(
        delta, dbc, xs, A_log + (size_t)l * DINNER * DSTATE, pf, hf);
    scan_phase2<<<128, 256, 0, stream>>>(pf, hf);
    scan_phase3<<<BB * CHUNKS * 8, 256, 0, stream>>>(
        delta, dbc, xs, xz, A_log + (size_t)l * DINNER * DSTATE,
        Dp + (size_t)l * DINNER, pf, ybb);
    // out_proj (+residual): h += yb_bf16 @ wO^T  [MFMA]
    gemm_bf16<1><<<dim3(256 / 128, 8192 / 128), 256, 0, stream>>>(
        ybb, wO, h, TOK, DMODEL, DINNER);
  }
}

// Round 5
// 382.447 us; speedup vs baseline: 9.0720x; 1.2977x over previous
//
#include <hip/hip_runtime.h>
#include <hip/hip_bf16.h>
#include <math.h>

// Problem constants
#define BB 4
#define WW 2048
#define TOK (BB * WW)        // 8192
#define DMODEL 256
#define DINNER 512
#define DSTATE 16
#define DTRANK 16
#define DCONV 4
#define NLAYERS 2
#define CHUNKS 64
#define CLEN (WW / CHUNKS)   // 32

typedef __attribute__((ext_vector_type(8))) short short8;
typedef __attribute__((ext_vector_type(4))) float floatx4;

static __device__ __forceinline__ unsigned short f2bf(float f) {
  __hip_bfloat16 b = __float2bfloat16(f);
  return *(unsigned short*)&b;
}

static __device__ __forceinline__ void load_lds16(const void* g, void* l) {
  __builtin_amdgcn_global_load_lds(
      (const __attribute__((address_space(1))) unsigned int*)g,
      (__attribute__((address_space(3))) unsigned int*)l, 16, 0, 0);
}

// ---------------------------------------------------------------------------
// Embed: h[tok][d] = x[tok] * emb_w[d] + emb_b[d]
// ---------------------------------------------------------------------------
__global__ __launch_bounds__(256) void embed_kernel(
    const float* __restrict__ x, const float* __restrict__ ew,
    const float* __restrict__ eb, float* __restrict__ h) {
  int idx = blockIdx.x * 256 + threadIdx.x;
  int tok = idx >> 6;
  int d4 = (idx & 63) * 4;
  float xv = x[tok];
  float4 w = *(const float4*)&ew[d4];
  float4 b = *(const float4*)&eb[d4];
  float4 o;
  o.x = xv * w.x + b.x;
  o.y = xv * w.y + b.y;
  o.z = xv * w.z + b.z;
  o.w = xv * w.w + b.w;
  *(float4*)&h[(size_t)tok * DMODEL + d4] = o;
}

// ---------------------------------------------------------------------------
// RMSNorm: one wave per token; output cast to bf16 (in_proj MFMA A-operand)
// ---------------------------------------------------------------------------
__global__ __launch_bounds__(256) void rmsnorm_kernel(
    const float* __restrict__ h, const float* __restrict__ w,
    unsigned short* __restrict__ ub) {
  int wave = threadIdx.x >> 6;
  int lane = threadIdx.x & 63;
  int tok = blockIdx.x * 4 + wave;
  const float* hp = h + (size_t)tok * DMODEL;
  float4 v = *(const float4*)&hp[lane * 4];
  float ss = v.x * v.x + v.y * v.y + v.z * v.z + v.w * v.w;
#pragma unroll
  for (int off = 32; off; off >>= 1) ss += __shfl_xor(ss, off, 64);
  float rs = rsqrtf(ss * (1.0f / 256.0f) + 1e-5f);
  float4 wv = *(const float4*)&w[lane * 4];
  ushort4 o;
  o.x = f2bf(v.x * rs * wv.x);
  o.y = f2bf(v.y * rs * wv.y);
  o.z = f2bf(v.z * rs * wv.z);
  o.w = f2bf(v.w * rs * wv.w);
  *(ushort4*)&ub[(size_t)tok * DMODEL + lane * 4] = o;
}

// ---------------------------------------------------------------------------
// fp32 -> bf16 cast, 4 elements/thread
// ---------------------------------------------------------------------------
__global__ __launch_bounds__(256) void cast_bf16_kernel(
    const float* __restrict__ src, unsigned short* __restrict__ dst) {
  int i = (blockIdx.x * 256 + threadIdx.x) * 4;
  float4 v = *(const float4*)&src[i];
  ushort4 o = {f2bf(v.x), f2bf(v.y), f2bf(v.z), f2bf(v.w)};
  *(ushort4*)&dst[i] = o;
}

// ---------------------------------------------------------------------------
// bf16 MFMA GEMM: C[M,N] (+)= A[M,K] * B[N,K]^T.  128x128 tile, BK=32.
// ---------------------------------------------------------------------------
template <int EPI>
__global__ __launch_bounds__(256) void gemm_bf16(
    const unsigned short* __restrict__ A, const unsigned short* __restrict__ Bw,
    float* __restrict__ C, int M, int N, int K) {
  __shared__ unsigned short As[128 * 32];   // row-major 128 x 32, 64 B rows
  __shared__ unsigned short Bs[128 * 32];
  int tid = threadIdx.x;
  int wave = tid >> 6;
  int lane = tid & 63;
  int wm = (wave & 1) * 64;
  int wn = (wave >> 1) * 64;
  int m0 = blockIdx.y * 128;
  int n0 = blockIdx.x * 128;
  int mlane = lane & 15;
  int quad = lane >> 4;
  floatx4 acc[4][4] = {};

  for (int k0 = 0; k0 < K; k0 += 32) {
#pragma unroll
    for (int i = 0; i < 2; i++) {
      int off = i * 4096 + wave * 1024 + lane * 16;
      int row = off >> 6;
      int col = off & 63;
      load_lds16((const char*)A + ((size_t)(m0 + row) * K + k0) * 2 + col,
                 (char*)As + i * 4096 + wave * 1024);
    }
#pragma unroll
    for (int i = 0; i < 2; i++) {
      int off = i * 4096 + wave * 1024 + lane * 16;
      int row = off >> 6;
      int col = off & 63;
      load_lds16((const char*)Bw + ((size_t)(n0 + row) * K + k0) * 2 + col,
                 (char*)Bs + i * 4096 + wave * 1024);
    }
    __syncthreads();
    short8 af[4], bf[4];
#pragma unroll
    for (int i = 0; i < 4; i++)
      af[i] = *(const short8*)((const char*)As + (wm + i * 16 + mlane) * 64 + quad * 16);
#pragma unroll
    for (int j = 0; j < 4; j++)
      bf[j] = *(const short8*)((const char*)Bs + (wn + j * 16 + mlane) * 64 + quad * 16);
#pragma unroll
    for (int i = 0; i < 4; i++)
#pragma unroll
      for (int j = 0; j < 4; j++)
        acc[i][j] = __builtin_amdgcn_mfma_f32_16x16x32_bf16(af[i], bf[j], acc[i][j], 0, 0, 0);
    __syncthreads();
  }

#pragma unroll
  for (int i = 0; i < 4; i++) {
#pragma unroll
    for (int j = 0; j < 4; j++) {
      int n = n0 + wn + j * 16 + mlane;
#pragma unroll
      for (int r = 0; r < 4; r++) {
        int m = m0 + wm + i * 16 + quad * 4 + r;
        float* p = &C[(size_t)m * N + n];
        float v = acc[i][j][r];
        if (EPI == 1) v += *p;
        *p = v;
      }
    }
  }
}

// ---------------------------------------------------------------------------
// fp32 SGEMM (x_proj, N=48): C[M,N] = A[M,K]*B[N,K]^T.  BM templated; BM=32
// gives 256 blocks for the skinny dispatch.
// ---------------------------------------------------------------------------
template <int EPI, int BM>
__global__ __launch_bounds__(256) void gemm_nt(
    const float* __restrict__ A, const float* __restrict__ Bw,
    float* __restrict__ C, int M, int N, int K) {
  __shared__ float As[32][BM];
  __shared__ float Bs[32][64];
  const int RP = BM / 16;          // rows per thread
  int tid = threadIdx.x;
  int m0 = blockIdx.y * BM;
  int n0 = blockIdx.x * 64;
  int tx = tid & 15;
  int ty = tid >> 4;
  float acc[RP][4] = {};

  for (int k0 = 0; k0 < K; k0 += 32) {
    {
      int r = tid >> 3;            // 0..31
      int c = (tid & 7) * 4;
#pragma unroll
      for (int i = 0; i < BM / 32; i++) {
        int row = r + i * 32;
        float4 v = *(const float4*)&A[(size_t)(m0 + row) * K + k0 + c];
        As[c + 0][row] = v.x;
        As[c + 1][row] = v.y;
        As[c + 2][row] = v.z;
        As[c + 3][row] = v.w;
      }
    }
    {
      int rb = tid >> 2;
      int cb = (tid & 3) * 8;
#pragma unroll
      for (int i = 0; i < 2; i++) {
        int col = cb + i * 4;
        float4 v = make_float4(0.f, 0.f, 0.f, 0.f);
        if (n0 + rb < N) v = *(const float4*)&Bw[(size_t)(n0 + rb) * K + k0 + col];
        Bs[col + 0][rb] = v.x;
        Bs[col + 1][rb] = v.y;
        Bs[col + 2][rb] = v.z;
        Bs[col + 3][rb] = v.w;
      }
    }
    __syncthreads();
#pragma unroll
    for (int kk = 0; kk < 32; kk++) {
      float av[RP];
#pragma unroll
      for (int i = 0; i < RP; i++) av[i] = As[kk][ty * RP + i];
      float4 b = *(const float4*)&Bs[kk][tx * 4];
      float bv[4] = {b.x, b.y, b.z, b.w};
#pragma unroll
      for (int i = 0; i < RP; i++)
#pragma unroll
        for (int j = 0; j < 4; j++) acc[i][j] = fmaf(av[i], bv[j], acc[i][j]);
    }
    __syncthreads();
  }

  int n = n0 + tx * 4;
  if (n < N) {
#pragma unroll
    for (int i = 0; i < RP; i++) {
      int m = m0 + ty * RP + i;
      float* p = &C[(size_t)m * N + n];
      float4 v = {acc[i][0], acc[i][1], acc[i][2], acc[i][3]};
      if (EPI == 1) {
        float4 o = *(const float4*)p;
        v.x += o.x; v.y += o.y; v.z += o.z; v.w += o.w;
      }
      *(float4*)p = v;
    }
  }
}

// ---------------------------------------------------------------------------
// Causal depthwise conv (D_CONV=4) + SiLU.
// ---------------------------------------------------------------------------
__global__ __launch_bounds__(256) void conv_silu_kernel(
    const float* __restrict__ xz, const float* __restrict__ cw,
    const float* __restrict__ cb, float* __restrict__ xs) {
  int idx = blockIdx.x * 256 + threadIdx.x;
  int tok = idx >> 7;
  int c4 = (idx & 127) * 4;
  int b = tok >> 11;
  int t = tok & (WW - 1);
  float wch[4][4];
#pragma unroll
  for (int c = 0; c < 4; c++) {
    float4 w = *(const float4*)&cw[(c4 + c) * DCONV];
    wch[c][0] = w.x; wch[c][1] = w.y; wch[c][2] = w.z; wch[c][3] = w.w;
  }
  float4 bias = *(const float4*)&cb[c4];
  float acc[4] = {bias.x, bias.y, bias.z, bias.w};
#pragma unroll
  for (int k = 0; k < 4; k++) {
    int tt = t - 3 + k;
    if (tt >= 0) {
      float4 xv = *(const float4*)&xz[((size_t)(b * WW + tt)) * (2 * DINNER) + c4];
      acc[0] = fmaf(xv.x, wch[0][k], acc[0]);
      acc[1] = fmaf(xv.y, wch[1][k], acc[1]);
      acc[2] = fmaf(xv.z, wch[2][k], acc[2]);
      acc[3] = fmaf(xv.w, wch[3][k], acc[3]);
    }
  }
  float4 o;
  o.x = acc[0] / (1.f + __expf(-acc[0]));
  o.y = acc[1] / (1.f + __expf(-acc[1]));
  o.z = acc[2] / (1.f + __expf(-acc[2]));
  o.w = acc[3] / (1.f + __expf(-acc[3]));
  *(float4*)&xs[(size_t)tok * DINNER + c4] = o;
}

// ---------------------------------------------------------------------------
// dt projection + softplus (stable fast form)
// ---------------------------------------------------------------------------
__global__ __launch_bounds__(256) void dt_kernel(
    const float* __restrict__ dbc, const float* __restrict__ dtw,
    const float* __restrict__ dtb, float* __restrict__ delta) {
  __shared__ float ws[512][17];
  __shared__ float ds[16][16];
  int tid = threadIdx.x;
  int tok0 = blockIdx.x * 16;
#pragma unroll
  for (int i = 0; i < 2; i++) {
    int r = tid * 2 + i;
#pragma unroll
    for (int j = 0; j < 4; j++) {
      float4 v = *(const float4*)&dtw[r * 16 + j * 4];
      ws[r][j * 4 + 0] = v.x;
      ws[r][j * 4 + 1] = v.y;
      ws[r][j * 4 + 2] = v.z;
      ws[r][j * 4 + 3] = v.w;
    }
  }
  if (tid < 64) {
    int m = tid >> 2, j = (tid & 3) * 4;
    *(float4*)&ds[m][j] = *(const float4*)&dbc[(size_t)(tok0 + m) * 48 + j];
  }
  __syncthreads();
#pragma unroll
  for (int pass = 0; pass < 2; pass++) {
    int n = tid + pass * 256;
    float w[16];
#pragma unroll
    for (int r = 0; r < 16; r++) w[r] = ws[n][r];
    float bias = dtb[n];
#pragma unroll
    for (int m = 0; m < 16; m++) {
      float s = bias;
#pragma unroll
      for (int r = 0; r < 16; r++) s = fmaf(ds[m][r], w[r], s);
      float sp = fmaxf(s, 0.f) + __logf(1.f + __expf(-fabsf(s)));
      delta[(size_t)(tok0 + m) * DINNER + n] = sp;
    }
  }
}

// ---------------------------------------------------------------------------
// Chunked selective scan, 16 states per thread, d across lanes.
// Thread owns one d-channel; delta/u/z/y fully coalesced (256 B/wave);
// B/C are wave-uniform (scalar loads); C-dot in-register, no shuffles.
// Grid = BB*CHUNKS*2 blocks of 256 threads (d = dblk*256 + tid).
// ---------------------------------------------------------------------------
__global__ __launch_bounds__(256) void scan_phase1(
    const float* __restrict__ delta, const float* __restrict__ dbc,
    const float* __restrict__ xs, const float* __restrict__ A_log,
    float* __restrict__ Pfin, float* __restrict__ Hfin) {
  int blk = blockIdx.x;            // (b*CHUNKS + c)*2 + dblk
  int dblk = blk & 1;
  int bc = blk >> 1;
  int c = bc & (CHUNKS - 1);
  int b = bc >> 6;                 // log2(CHUNKS)
  int d = dblk * 256 + threadIdx.x;
  float A[16];
#pragma unroll
  for (int j = 0; j < 4; j++) {
    float4 v = *(const float4*)&A_log[d * DSTATE + j * 4];
    A[4 * j + 0] = -__expf(v.x);
    A[4 * j + 1] = -__expf(v.y);
    A[4 * j + 2] = -__expf(v.z);
    A[4 * j + 3] = -__expf(v.w);
  }
  float h[16], P[16];
#pragma unroll
  for (int s = 0; s < 16; s++) { h[s] = 0.f; P[s] = 1.f; }
  int t0 = c * CLEN;
  const float* dp_ = delta + ((size_t)(b * WW + t0)) * DINNER + d;
  const float* up_ = xs + ((size_t)(b * WW + t0)) * DINNER + d;
  const float* bcp = dbc + ((size_t)(b * WW + t0)) * 48 + DTRANK;
#pragma unroll 4
  for (int t = 0; t < CLEN; t++) {
    float dv = dp_[(size_t)t * DINNER];
    float uv = up_[(size_t)t * DINNER];
    float Bv[16];
#pragma unroll
    for (int j = 0; j < 4; j++) {
      float4 q = *(const float4*)&bcp[t * 48 + j * 4];
      Bv[4 * j + 0] = q.x; Bv[4 * j + 1] = q.y;
      Bv[4 * j + 2] = q.z; Bv[4 * j + 3] = q.w;
    }
    float du = dv * uv;
#pragma unroll
    for (int s = 0; s < 16; s++) {
      float e = __expf(dv * A[s]);
      P[s] *= e;
      h[s] = fmaf(e, h[s], du * Bv[s]);
    }
  }
  size_t o = ((size_t)(b * DINNER + d) * CHUNKS + c) * DSTATE;
#pragma unroll
  for (int j = 0; j < 4; j++) {
    float4 pv = {P[4 * j], P[4 * j + 1], P[4 * j + 2], P[4 * j + 3]};
    float4 hv = {h[4 * j], h[4 * j + 1], h[4 * j + 2], h[4 * j + 3]};
    *(float4*)&Pfin[o + 4 * j] = pv;
    *(float4*)&Hfin[o + 4 * j] = hv;
  }
}

// In-place: carry-in overwrites Pfin.
__global__ __launch_bounds__(256) void scan_phase2(
    float* __restrict__ Pfin, const float* __restrict__ Hfin) {
  int idx = blockIdx.x * 256 + threadIdx.x;  // 32768 = g*16+s
  int s = idx & 15;
  int g = idx >> 4;
  float h = 0.f;
#pragma unroll
  for (int c = 0; c < CHUNKS; c++) {
    size_t o = ((size_t)g * CHUNKS + c) * DSTATE + s;
    float P = Pfin[o];
    float f = Hfin[o];
    Pfin[o] = h;             // carry-in for chunk c
    h = fmaf(P, h, f);
  }
}

__global__ __launch_bounds__(256) void scan_phase3(
    const float* __restrict__ delta, const float* __restrict__ dbc,
    const float* __restrict__ xs, const float* __restrict__ xz,
    const float* __restrict__ A_log, const float* __restrict__ Dp,
    const float* __restrict__ Hin, unsigned short* __restrict__ yb) {
  int blk = blockIdx.x;
  int dblk = blk & 1;
  int bc = blk >> 1;
  int c = bc & (CHUNKS - 1);
  int b = bc >> 6;
  int d = dblk * 256 + threadIdx.x;
  float A[16];
#pragma unroll
  for (int j = 0; j < 4; j++) {
    float4 v = *(const float4*)&A_log[d * DSTATE + j * 4];
    A[4 * j + 0] = -__expf(v.x);
    A[4 * j + 1] = -__expf(v.y);
    A[4 * j + 2] = -__expf(v.z);
    A[4 * j + 3] = -__expf(v.w);
  }
  float Dv = Dp[d];
  float h[16];
  size_t o = ((size_t)(b * DINNER + d) * CHUNKS + c) * DSTATE;
#pragma unroll
  for (int j = 0; j < 4; j++) {
    float4 hv = *(const float4*)&Hin[o + 4 * j];
    h[4 * j + 0] = hv.x; h[4 * j + 1] = hv.y;
    h[4 * j + 2] = hv.z; h[4 * j + 3] = hv.w;
  }
  int t0 = c * CLEN;
  const float* dp_ = delta + ((size_t)(b * WW + t0)) * DINNER + d;
  const float* up_ = xs + ((size_t)(b * WW + t0)) * DINNER + d;
  const float* bcp = dbc + ((size_t)(b * WW + t0)) * 48 + DTRANK;
  const float* zb = xz + ((size_t)(b * WW + t0)) * (2 * DINNER) + DINNER + d;
  unsigned short* yp = yb + ((size_t)(b * WW + t0)) * DINNER + d;
#pragma unroll 4
  for (int t = 0; t < CLEN; t++) {
    float dv = dp_[(size_t)t * DINNER];
    float uv = up_[(size_t)t * DINNER];
    float zv = zb[(size_t)t * (2 * DINNER)];
    float Bv[16], Cv[16];
#pragma unroll
    for (int j = 0; j < 4; j++) {
      float4 q = *(const float4*)&bcp[t * 48 + j * 4];
      Bv[4 * j + 0] = q.x; Bv[4 * j + 1] = q.y;
      Bv[4 * j + 2] = q.z; Bv[4 * j + 3] = q.w;
      float4 r = *(const float4*)&bcp[t * 48 + DSTATE + j * 4];
      Cv[4 * j + 0] = r.x; Cv[4 * j + 1] = r.y;
      Cv[4 * j + 2] = r.z; Cv[4 * j + 3] = r.w;
    }
    float du = dv * uv;
    float p = 0.f;
#pragma unroll
    for (int s = 0; s < 16; s++) {
      float e = __expf(dv * A[s]);
      h[s] = fmaf(e, h[s], du * Bv[s]);
      p = fmaf(h[s], Cv[s], p);
    }
    float yv = fmaf(uv, Dv, p);
    yv *= zv / (1.f + __expf(-zv));
    yp[(size_t)t * DINNER] = f2bf(yv);
  }
}

// ---------------------------------------------------------------------------
extern "C" void kernel_launch(void* const* d_in, const int* in_sizes, int n_in,
                              void* d_out, int out_size, void* d_ws, size_t ws_size,
                              hipStream_t stream) {
  const float* x = (const float*)d_in[0];
  const float* emb_w = (const float*)d_in[1];
  const float* emb_b = (const float*)d_in[2];
  const float* in_proj_w = (const float*)d_in[3];
  const float* conv_w = (const float*)d_in[4];
  const float* conv_b = (const float*)d_in[5];
  const float* x_proj_w = (const float*)d_in[6];
  const float* dt_proj_w = (const float*)d_in[7];
  const float* dt_proj_b = (const float*)d_in[8];
  const float* A_log = (const float*)d_in[9];
  const float* Dp = (const float*)d_in[10];
  const float* out_proj_w = (const float*)d_in[11];
  const float* norm_w = (const float*)d_in[12];

  float* h = (float*)d_out;                       // (8192, 256)
  float* ws = (float*)d_ws;
  // Region map (floats from ws base), ~20.9M floats total:
  //   [0,2M)       : ub bf16 (1M fl-eq) -> pf (2M fl) during scan
  //   [2M,10M)     : xz (8192x1024 fp32)
  //   [10M,14M)    : xs (8192x512 fp32)
  //   [14M,14.5M)  : dbc (8192x48 fp32)
  //   [14.5M,18.5M): delta
  //   [18.5M,20.5M): hf (2M fl) -> ybb bf16 (2M fl-eq) in phase3
  //   [20.5M, ...) : wA_all (524288 bf16), wO_all (262144 bf16)
  const size_t M1 = 1024 * 1024;
  unsigned short* ub = (unsigned short*)ws;
  float* pf = ws;
  float* xz = ws + 2 * M1;
  float* xs = ws + 10 * M1;
  float* dbc = ws + 14 * M1;
  float* delta = ws + 14 * M1 + 524288;
  float* hf = ws + 18 * M1 + 524288;
  unsigned short* ybb = (unsigned short*)hf;
  unsigned short* wA_all = (unsigned short*)(ws + 20 * M1 + 524288);
  unsigned short* wO_all = wA_all + (size_t)NLAYERS * 2 * DINNER * DMODEL;

  // Hoisted weight casts (both layers contiguous in the input tensors)
  cast_bf16_kernel<<<512, 256, 0, stream>>>(in_proj_w, wA_all);   // 2*524288 el
  cast_bf16_kernel<<<256, 256, 0, stream>>>(out_proj_w, wO_all);  // 2*131072 el

  embed_kernel<<<2048, 256, 0, stream>>>(x, emb_w, emb_b, h);

  for (int l = 0; l < NLAYERS; l++) {
    const unsigned short* wA = wA_all + (size_t)l * 2 * DINNER * DMODEL;
    const unsigned short* wO = wO_all + (size_t)l * DMODEL * DINNER;

    rmsnorm_kernel<<<2048, 256, 0, stream>>>(h, norm_w + l * DMODEL, ub);
    // in_proj: (8192,1024) = u_bf16 @ wA^T  [MFMA]
    gemm_bf16<0><<<dim3(1024 / 128, 8192 / 128), 256, 0, stream>>>(
        ub, wA, xz, TOK, 2 * DINNER, DMODEL);
    conv_silu_kernel<<<4096, 256, 0, stream>>>(
        xz, conv_w + (size_t)l * DINNER * DCONV, conv_b + (size_t)l * DINNER, xs);
    // x_proj: (8192,48) = xs @ W^T  [fp32, BM=32 -> 256 blocks]
    gemm_nt<0, 32><<<dim3(1, 8192 / 32), 256, 0, stream>>>(
        xs, x_proj_w + (size_t)l * 48 * DINNER, dbc, TOK, 48, DINNER);
    dt_kernel<<<512, 256, 0, stream>>>(
        dbc, dt_proj_w + (size_t)l * DINNER * DTRANK, dt_proj_b + (size_t)l * DINNER, delta);
    // Chunked scan: 512 blocks = (b*CHUNKS + c)*2 + dblk
    scan_phase1<<<BB * CHUNKS * 2, 256, 0, stream>>>(
        delta, dbc, xs, A_log + (size_t)l * DINNER * DSTATE, pf, hf);
    scan_phase2<<<128, 256, 0, stream>>>(pf, hf);
    scan_phase3<<<BB * CHUNKS * 2, 256, 0, stream>>>(
        delta, dbc, xs, xz, A_log + (size_t)l * DINNER * DSTATE,
        Dp + (size_t)l * DINNER, pf, ybb);
    // out_proj (+residual): h += yb_bf16 @ wO^T  [MFMA]
    gemm_bf16<1><<<dim3(256 / 128, 8192 / 128), 256, 0, stream>>>(
        ybb, wO, h, TOK, DMODEL, DINNER);
  }
}

// Round 7
// 363.118 us; speedup vs baseline: 9.5549x; 1.0532x over previous
//
#include <hip/hip_runtime.h>
#include <hip/hip_bf16.h>
#include <math.h>

// Problem constants
#define BB 4
#define WW 2048
#define TOK (BB * WW)        // 8192
#define DMODEL 256
#define DINNER 512
#define DSTATE 16
#define DTRANK 16
#define DCONV 4
#define NLAYERS 2
#define CHUNKS 64
#define CLEN (WW / CHUNKS)   // 32

typedef __attribute__((ext_vector_type(8))) short short8;
typedef __attribute__((ext_vector_type(4))) float floatx4;

static __device__ __forceinline__ unsigned short f2bf(float f) {
  __hip_bfloat16 b = __float2bfloat16(f);
  return *(unsigned short*)&b;
}
static __device__ __forceinline__ float bf2f(unsigned short u) {
  union { unsigned int i; float f; } x;
  x.i = ((unsigned int)u) << 16;
  return x.f;
}

static __device__ __forceinline__ void load_lds16(const void* g, void* l) {
  __builtin_amdgcn_global_load_lds(
      (const __attribute__((address_space(1))) unsigned int*)g,
      (__attribute__((address_space(3))) unsigned int*)l, 16, 0, 0);
}

// ---------------------------------------------------------------------------
// Fused embed + RMSNorm (layer 0): h = x*ew+eb; ub = rmsnorm(h)*nw (bf16)
// ---------------------------------------------------------------------------
__global__ __launch_bounds__(256) void embed_rms_kernel(
    const float* __restrict__ x, const float* __restrict__ ew,
    const float* __restrict__ eb, const float* __restrict__ nw,
    float* __restrict__ h, unsigned short* __restrict__ ub) {
  int wave = threadIdx.x >> 6;
  int lane = threadIdx.x & 63;
  int tok = blockIdx.x * 4 + wave;
  int d4 = lane * 4;
  float xv = x[tok];
  float4 w = *(const float4*)&ew[d4];
  float4 b = *(const float4*)&eb[d4];
  float4 e;
  e.x = xv * w.x + b.x;
  e.y = xv * w.y + b.y;
  e.z = xv * w.z + b.z;
  e.w = xv * w.w + b.w;
  *(float4*)&h[(size_t)tok * DMODEL + d4] = e;
  float ss = e.x * e.x + e.y * e.y + e.z * e.z + e.w * e.w;
#pragma unroll
  for (int off = 32; off; off >>= 1) ss += __shfl_xor(ss, off, 64);
  float rs = rsqrtf(ss * (1.0f / 256.0f) + 1e-5f);
  float4 nv = *(const float4*)&nw[d4];
  ushort4 o;
  o.x = f2bf(e.x * rs * nv.x);
  o.y = f2bf(e.y * rs * nv.y);
  o.z = f2bf(e.z * rs * nv.z);
  o.w = f2bf(e.w * rs * nv.w);
  *(ushort4*)&ub[(size_t)tok * DMODEL + d4] = o;
}

// ---------------------------------------------------------------------------
// RMSNorm (layer >=1): one wave per token; bf16 out
// ---------------------------------------------------------------------------
__global__ __launch_bounds__(256) void rmsnorm_kernel(
    const float* __restrict__ h, const float* __restrict__ w,
    unsigned short* __restrict__ ub) {
  int wave = threadIdx.x >> 6;
  int lane = threadIdx.x & 63;
  int tok = blockIdx.x * 4 + wave;
  const float* hp = h + (size_t)tok * DMODEL;
  float4 v = *(const float4*)&hp[lane * 4];
  float ss = v.x * v.x + v.y * v.y + v.z * v.z + v.w * v.w;
#pragma unroll
  for (int off = 32; off; off >>= 1) ss += __shfl_xor(ss, off, 64);
  float rs = rsqrtf(ss * (1.0f / 256.0f) + 1e-5f);
  float4 wv = *(const float4*)&w[lane * 4];
  ushort4 o;
  o.x = f2bf(v.x * rs * wv.x);
  o.y = f2bf(v.y * rs * wv.y);
  o.z = f2bf(v.z * rs * wv.z);
  o.w = f2bf(v.w * rs * wv.w);
  *(ushort4*)&ub[(size_t)tok * DMODEL + lane * 4] = o;
}

// ---------------------------------------------------------------------------
// fp32 -> bf16 cast, 4 elements/thread
// ---------------------------------------------------------------------------
__global__ __launch_bounds__(256) void cast_bf16_kernel(
    const float* __restrict__ src, unsigned short* __restrict__ dst) {
  int i = (blockIdx.x * 256 + threadIdx.x) * 4;
  float4 v = *(const float4*)&src[i];
  ushort4 o = {f2bf(v.x), f2bf(v.y), f2bf(v.z), f2bf(v.w)};
  *(ushort4*)&dst[i] = o;
}

// ---------------------------------------------------------------------------
// bf16 MFMA GEMM: 128x128 tile, BK=32.
// EPI=1: C[M,N] += A*B^T (residual add, fp32 C)
// EPI=2: in_proj split epilogue: cols <512 -> fp32 xc, cols >=512 -> bf16 zb
// ---------------------------------------------------------------------------
template <int EPI>
__global__ __launch_bounds__(256) void gemm_bf16(
    const unsigned short* __restrict__ A, const unsigned short* __restrict__ Bw,
    float* __restrict__ C, unsigned short* __restrict__ Cz,
    int M, int N, int K) {
  __shared__ unsigned short As[128 * 32];   // row-major 128 x 32, 64 B rows
  __shared__ unsigned short Bs[128 * 32];
  int tid = threadIdx.x;
  int wave = tid >> 6;
  int lane = tid & 63;
  int wm = (wave & 1) * 64;
  int wn = (wave >> 1) * 64;
  int m0 = blockIdx.y * 128;
  int n0 = blockIdx.x * 128;
  int mlane = lane & 15;
  int quad = lane >> 4;
  floatx4 acc[4][4] = {};

  for (int k0 = 0; k0 < K; k0 += 32) {
#pragma unroll
    for (int i = 0; i < 2; i++) {
      int off = i * 4096 + wave * 1024 + lane * 16;
      int row = off >> 6;
      int col = off & 63;
      load_lds16((const char*)A + ((size_t)(m0 + row) * K + k0) * 2 + col,
                 (char*)As + i * 4096 + wave * 1024);
    }
#pragma unroll
    for (int i = 0; i < 2; i++) {
      int off = i * 4096 + wave * 1024 + lane * 16;
      int row = off >> 6;
      int col = off & 63;
      load_lds16((const char*)Bw + ((size_t)(n0 + row) * K + k0) * 2 + col,
                 (char*)Bs + i * 4096 + wave * 1024);
    }
    __syncthreads();
    short8 af[4], bf[4];
#pragma unroll
    for (int i = 0; i < 4; i++)
      af[i] = *(const short8*)((const char*)As + (wm + i * 16 + mlane) * 64 + quad * 16);
#pragma unroll
    for (int j = 0; j < 4; j++)
      bf[j] = *(const short8*)((const char*)Bs + (wn + j * 16 + mlane) * 64 + quad * 16);
#pragma unroll
    for (int i = 0; i < 4; i++)
#pragma unroll
      for (int j = 0; j < 4; j++)
        acc[i][j] = __builtin_amdgcn_mfma_f32_16x16x32_bf16(af[i], bf[j], acc[i][j], 0, 0, 0);
    __syncthreads();
  }

#pragma unroll
  for (int i = 0; i < 4; i++) {
#pragma unroll
    for (int j = 0; j < 4; j++) {
      int n = n0 + wn + j * 16 + mlane;
#pragma unroll
      for (int r = 0; r < 4; r++) {
        int m = m0 + wm + i * 16 + quad * 4 + r;
        float v = acc[i][j][r];
        if (EPI == 2) {
          if (n < DINNER) C[(size_t)m * DINNER + n] = v;
          else Cz[(size_t)m * DINNER + (n - DINNER)] = f2bf(v);
        } else {
          float* p = &C[(size_t)m * N + n];
          if (EPI == 1) v += *p;
          *p = v;
        }
      }
    }
  }
}

// ---------------------------------------------------------------------------
// x_proj GEMM: C[M,48] = A_bf16[M,512] * B_fp32[48,512]^T.  BM=32, BK=32.
// ---------------------------------------------------------------------------
template <int BM>
__global__ __launch_bounds__(256) void gemm_bf16a(
    const unsigned short* __restrict__ A, const float* __restrict__ Bw,
    float* __restrict__ C, int M, int N, int K) {
  __shared__ float As[32][BM];
  __shared__ float Bs[32][64];
  const int RP = BM / 16;          // 2
  int tid = threadIdx.x;
  int m0 = blockIdx.y * BM;
  int n0 = blockIdx.x * 64;
  int tx = tid & 15;
  int ty = tid >> 4;
  float acc[RP][4] = {};

  for (int k0 = 0; k0 < K; k0 += 32) {
    {
      int r = tid >> 3;            // 0..31
      int c = (tid & 7) * 4;
      ushort4 a = *(const ushort4*)&A[(size_t)(m0 + r) * K + k0 + c];
      As[c + 0][r] = bf2f(a.x);
      As[c + 1][r] = bf2f(a.y);
      As[c + 2][r] = bf2f(a.z);
      As[c + 3][r] = bf2f(a.w);
    }
    {
      int rb = tid >> 2;
      int cb = (tid & 3) * 8;
#pragma unroll
      for (int i = 0; i < 2; i++) {
        int col = cb + i * 4;
        float4 v = make_float4(0.f, 0.f, 0.f, 0.f);
        if (n0 + rb < N) v = *(const float4*)&Bw[(size_t)(n0 + rb) * K + k0 + col];
        Bs[col + 0][rb] = v.x;
        Bs[col + 1][rb] = v.y;
        Bs[col + 2][rb] = v.z;
        Bs[col + 3][rb] = v.w;
      }
    }
    __syncthreads();
#pragma unroll
    for (int kk = 0; kk < 32; kk++) {
      float av[RP];
#pragma unroll
      for (int i = 0; i < RP; i++) av[i] = As[kk][ty * RP + i];
      float4 b = *(const float4*)&Bs[kk][tx * 4];
      float bv[4] = {b.x, b.y, b.z, b.w};
#pragma unroll
      for (int i = 0; i < RP; i++)
#pragma unroll
        for (int j = 0; j < 4; j++) acc[i][j] = fmaf(av[i], bv[j], acc[i][j]);
    }
    __syncthreads();
  }

  int n = n0 + tx * 4;
  if (n < N) {
#pragma unroll
    for (int i = 0; i < RP; i++) {
      int m = m0 + ty * RP + i;
      float4 v = {acc[i][0], acc[i][1], acc[i][2], acc[i][3]};
      *(float4*)&C[(size_t)m * N + n] = v;
    }
  }
}

// ---------------------------------------------------------------------------
// Causal depthwise conv + SiLU, sliding-window: xc read ONCE.
// Thread owns 4 channels x 16-token strip; 3-tap register window.
// ---------------------------------------------------------------------------
__global__ __launch_bounds__(256) void conv_silu_kernel(
    const float* __restrict__ xc, const float* __restrict__ cw,
    const float* __restrict__ cb, unsigned short* __restrict__ xs) {
  int idx = blockIdx.x * 256 + threadIdx.x;    // 65536
  int c4 = (idx & 127) * 4;
  int rest = idx >> 7;
  int strip = rest & 127;
  int b = rest >> 7;
  int t0 = strip * 16;
  float wch[4][4];
#pragma unroll
  for (int c = 0; c < 4; c++) {
    float4 w = *(const float4*)&cw[(c4 + c) * DCONV];
    wch[c][0] = w.x; wch[c][1] = w.y; wch[c][2] = w.z; wch[c][3] = w.w;
  }
  float4 bias = *(const float4*)&cb[c4];
  const float* xp = xc + ((size_t)b * WW) * DINNER + c4;
  float4 xm3 = make_float4(0, 0, 0, 0), xm2 = xm3, xm1 = xm3;
  if (t0 >= 3) xm3 = *(const float4*)&xp[(size_t)(t0 - 3) * DINNER];
  if (t0 >= 2) xm2 = *(const float4*)&xp[(size_t)(t0 - 2) * DINNER];
  if (t0 >= 1) xm1 = *(const float4*)&xp[(size_t)(t0 - 1) * DINNER];
  unsigned short* op = xs + ((size_t)b * WW) * DINNER + c4;
#pragma unroll 4
  for (int t = t0; t < t0 + 16; t++) {
    float4 xcur = *(const float4*)&xp[(size_t)t * DINNER];
    float a0 = bias.x, a1 = bias.y, a2 = bias.z, a3 = bias.w;
    a0 = fmaf(xm3.x, wch[0][0], fmaf(xm2.x, wch[0][1], fmaf(xm1.x, wch[0][2], fmaf(xcur.x, wch[0][3], a0))));
    a1 = fmaf(xm3.y, wch[1][0], fmaf(xm2.y, wch[1][1], fmaf(xm1.y, wch[1][2], fmaf(xcur.y, wch[1][3], a1))));
    a2 = fmaf(xm3.z, wch[2][0], fmaf(xm2.z, wch[2][1], fmaf(xm1.z, wch[2][2], fmaf(xcur.z, wch[2][3], a2))));
    a3 = fmaf(xm3.w, wch[3][0], fmaf(xm2.w, wch[3][1], fmaf(xm1.w, wch[3][2], fmaf(xcur.w, wch[3][3], a3))));
    ushort4 o;
    o.x = f2bf(a0 / (1.f + __expf(-a0)));
    o.y = f2bf(a1 / (1.f + __expf(-a1)));
    o.z = f2bf(a2 / (1.f + __expf(-a2)));
    o.w = f2bf(a3 / (1.f + __expf(-a3)));
    *(ushort4*)&op[(size_t)t * DINNER] = o;
    xm3 = xm2; xm2 = xm1; xm1 = xcur;
  }
}

// ---------------------------------------------------------------------------
// dt projection + softplus -> bf16 delta
// ---------------------------------------------------------------------------
__global__ __launch_bounds__(256) void dt_kernel(
    const float* __restrict__ dbc, const float* __restrict__ dtw,
    const float* __restrict__ dtb, unsigned short* __restrict__ delta) {
  __shared__ float ws[512][17];
  __shared__ float ds[16][16];
  int tid = threadIdx.x;
  int tok0 = blockIdx.x * 16;
#pragma unroll
  for (int i = 0; i < 2; i++) {
    int r = tid * 2 + i;
#pragma unroll
    for (int j = 0; j < 4; j++) {
      float4 v = *(const float4*)&dtw[r * 16 + j * 4];
      ws[r][j * 4 + 0] = v.x;
      ws[r][j * 4 + 1] = v.y;
      ws[r][j * 4 + 2] = v.z;
      ws[r][j * 4 + 3] = v.w;
    }
  }
  if (tid < 64) {
    int m = tid >> 2, j = (tid & 3) * 4;
    *(float4*)&ds[m][j] = *(const float4*)&dbc[(size_t)(tok0 + m) * 48 + j];
  }
  __syncthreads();
#pragma unroll
  for (int pass = 0; pass < 2; pass++) {
    int n = tid + pass * 256;
    float w[16];
#pragma unroll
    for (int r = 0; r < 16; r++) w[r] = ws[n][r];
    float bias = dtb[n];
#pragma unroll
    for (int m = 0; m < 16; m++) {
      float s = bias;
#pragma unroll
      for (int r = 0; r < 16; r++) s = fmaf(ds[m][r], w[r], s);
      float sp = fmaxf(s, 0.f) + __logf(1.f + __expf(-fabsf(s)));
      delta[(size_t)(tok0 + m) * DINNER + n] = f2bf(sp);
    }
  }
}

// ---------------------------------------------------------------------------
// Chunked selective scan, 16 states/thread, d across lanes; bf16 inputs.
// ---------------------------------------------------------------------------
__global__ __launch_bounds__(256) void scan_phase1(
    const unsigned short* __restrict__ delta, const float* __restrict__ dbc,
    const unsigned short* __restrict__ xs, const float* __restrict__ A_log,
    float* __restrict__ Pfin, float* __restrict__ Hfin) {
  int blk = blockIdx.x;            // (b*CHUNKS + c)*2 + dblk
  int dblk = blk & 1;
  int bc = blk >> 1;
  int c = bc & (CHUNKS - 1);
  int b = bc >> 6;
  int d = dblk * 256 + threadIdx.x;
  float A[16];
#pragma unroll
  for (int j = 0; j < 4; j++) {
    float4 v = *(const float4*)&A_log[d * DSTATE + j * 4];
    A[4 * j + 0] = -__expf(v.x);
    A[4 * j + 1] = -__expf(v.y);
    A[4 * j + 2] = -__expf(v.z);
    A[4 * j + 3] = -__expf(v.w);
  }
  float h[16], P[16];
#pragma unroll
  for (int s = 0; s < 16; s++) { h[s] = 0.f; P[s] = 1.f; }
  int t0 = c * CLEN;
  const unsigned short* dp_ = delta + ((size_t)(b * WW + t0)) * DINNER + d;
  const unsigned short* up_ = xs + ((size_t)(b * WW + t0)) * DINNER + d;
  const float* bcp = dbc + ((size_t)(b * WW + t0)) * 48 + DTRANK;
#pragma unroll 4
  for (int t = 0; t < CLEN; t++) {
    float dv = bf2f(dp_[(size_t)t * DINNER]);
    float uv = bf2f(up_[(size_t)t * DINNER]);
    float Bv[16];
#pragma unroll
    for (int j = 0; j < 4; j++) {
      float4 q = *(const float4*)&bcp[t * 48 + j * 4];
      Bv[4 * j + 0] = q.x; Bv[4 * j + 1] = q.y;
      Bv[4 * j + 2] = q.z; Bv[4 * j + 3] = q.w;
    }
    float du = dv * uv;
#pragma unroll
    for (int s = 0; s < 16; s++) {
      float e = __expf(dv * A[s]);
      P[s] *= e;
      h[s] = fmaf(e, h[s], du * Bv[s]);
    }
  }
  size_t o = ((size_t)(b * DINNER + d) * CHUNKS + c) * DSTATE;
#pragma unroll
  for (int j = 0; j < 4; j++) {
    float4 pv = {P[4 * j], P[4 * j + 1], P[4 * j + 2], P[4 * j + 3]};
    float4 hv = {h[4 * j], h[4 * j + 1], h[4 * j + 2], h[4 * j + 3]};
    *(float4*)&Pfin[o + 4 * j] = pv;
    *(float4*)&Hfin[o + 4 * j] = hv;
  }
}

// In-place: carry-in overwrites Pfin.
__global__ __launch_bounds__(256) void scan_phase2(
    float* __restrict__ Pfin, const float* __restrict__ Hfin) {
  int idx = blockIdx.x * 256 + threadIdx.x;  // 32768 = g*16+s
  int s = idx & 15;
  int g = idx >> 4;
  float h = 0.f;
#pragma unroll
  for (int c = 0; c < CHUNKS; c++) {
    size_t o = ((size_t)g * CHUNKS + c) * DSTATE + s;
    float P = Pfin[o];
    float f = Hfin[o];
    Pfin[o] = h;             // carry-in for chunk c
    h = fmaf(P, h, f);
  }
}

__global__ __launch_bounds__(256) void scan_phase3(
    const unsigned short* __restrict__ delta, const float* __restrict__ dbc,
    const unsigned short* __restrict__ xs, const unsigned short* __restrict__ zb,
    const float* __restrict__ A_log, const float* __restrict__ Dp,
    const float* __restrict__ Hin, unsigned short* __restrict__ yb) {
  int blk = blockIdx.x;
  int dblk = blk & 1;
  int bc = blk >> 1;
  int c = bc & (CHUNKS - 1);
  int b = bc >> 6;
  int d = dblk * 256 + threadIdx.x;
  float A[16];
#pragma unroll
  for (int j = 0; j < 4; j++) {
    float4 v = *(const float4*)&A_log[d * DSTATE + j * 4];
    A[4 * j + 0] = -__expf(v.x);
    A[4 * j + 1] = -__expf(v.y);
    A[4 * j + 2] = -__expf(v.z);
    A[4 * j + 3] = -__expf(v.w);
  }
  float Dv = Dp[d];
  float h[16];
  size_t o = ((size_t)(b * DINNER + d) * CHUNKS + c) * DSTATE;
#pragma unroll
  for (int j = 0; j < 4; j++) {
    float4 hv = *(const float4*)&Hin[o + 4 * j];
    h[4 * j + 0] = hv.x; h[4 * j + 1] = hv.y;
    h[4 * j + 2] = hv.z; h[4 * j + 3] = hv.w;
  }
  int t0 = c * CLEN;
  const unsigned short* dp_ = delta + ((size_t)(b * WW + t0)) * DINNER + d;
  const unsigned short* up_ = xs + ((size_t)(b * WW + t0)) * DINNER + d;
  const float* bcp = dbc + ((size_t)(b * WW + t0)) * 48 + DTRANK;
  const unsigned short* zp = zb + ((size_t)(b * WW + t0)) * DINNER + d;
  unsigned short* yp = yb + ((size_t)(b * WW + t0)) * DINNER + d;
#pragma unroll 4
  for (int t = 0; t < CLEN; t++) {
    float dv = bf2f(dp_[(size_t)t * DINNER]);
    float uv = bf2f(up_[(size_t)t * DINNER]);
    float zv = bf2f(zp[(size_t)t * DINNER]);
    float Bv[16], Cv[16];
#pragma unroll
    for (int j = 0; j < 4; j++) {
      float4 q = *(const float4*)&bcp[t * 48 + j * 4];
      Bv[4 * j + 0] = q.x; Bv[4 * j + 1] = q.y;
      Bv[4 * j + 2] = q.z; Bv[4 * j + 3] = q.w;
      float4 r = *(const float4*)&bcp[t * 48 + DSTATE + j * 4];
      Cv[4 * j + 0] = r.x; Cv[4 * j + 1] = r.y;
      Cv[4 * j + 2] = r.z; Cv[4 * j + 3] = r.w;
    }
    float du = dv * uv;
    float p = 0.f;
#pragma unroll
    for (int s = 0; s < 16; s++) {
      float e = __expf(dv * A[s]);
      h[s] = fmaf(e, h[s], du * Bv[s]);
      p = fmaf(h[s], Cv[s], p);
    }
    float yv = fmaf(uv, Dv, p);
    yv *= zv / (1.f + __expf(-zv));
    yp[(size_t)t * DINNER] = f2bf(yv);
  }
}

// ---------------------------------------------------------------------------
extern "C" void kernel_launch(void* const* d_in, const int* in_sizes, int n_in,
                              void* d_out, int out_size, void* d_ws, size_t ws_size,
                              hipStream_t stream) {
  const float* x = (const float*)d_in[0];
  const float* emb_w = (const float*)d_in[1];
  const float* emb_b = (const float*)d_in[2];
  const float* in_proj_w = (const float*)d_in[3];
  const float* conv_w = (const float*)d_in[4];
  const float* conv_b = (const float*)d_in[5];
  const float* x_proj_w = (const float*)d_in[6];
  const float* dt_proj_w = (const float*)d_in[7];
  const float* dt_proj_b = (const float*)d_in[8];
  const float* A_log = (const float*)d_in[9];
  const float* Dp = (const float*)d_in[10];
  const float* out_proj_w = (const float*)d_in[11];
  const float* norm_w = (const float*)d_in[12];

  float* h = (float*)d_out;                       // (8192, 256)
  float* ws = (float*)d_ws;
  // Region map in FLOAT-EQUIVALENT offsets (1 float = 2 bf16).
  // NOTE (R6 bug fix): every TOK x DINNER bf16 buffer = 4,194,304 elements
  // = 8 MB = 2M float-equivalents, NOT 1M.
  //   [0,1M)        : ub bf16 (TOKxDMODEL)   -> pf fp32 [0,2M) during scan
  //   [2M,6M)       : xc fp32 (TOKxDINNER)
  //   [6M,8M)       : zb bf16 (TOKxDINNER)
  //   [8M,10M)      : xs bf16 (TOKxDINNER)
  //   [10M,10.375M) : dbc fp32 (TOKx48)
  //   [10.5M,12.5M) : delta bf16 (TOKxDINNER)
  //   [12.5M,14.5M) : hf fp32 (2M)  -> ybb bf16 (TOKxDINNER) in phase3
  //   [14.5M,14.75M): wA_all bf16 (2x1024x256)
  //   [14.75M,14.875M): wO_all bf16 (2x256x512)
  // Total 14.875M floats = 59.5 MB (ws proven >= 90 MB in R2).
  const size_t M1 = 1024 * 1024;
  unsigned short* ub = (unsigned short*)ws;
  float* pf = ws;
  float* xc = ws + 2 * M1;
  unsigned short* zb = (unsigned short*)(ws + 6 * M1);
  unsigned short* xs = (unsigned short*)(ws + 8 * M1);
  float* dbc = ws + 10 * M1;
  unsigned short* delta = (unsigned short*)(ws + 10 * M1 + 524288);
  float* hf = ws + 12 * M1 + 524288;
  unsigned short* ybb = (unsigned short*)hf;
  unsigned short* wA_all = (unsigned short*)(ws + 14 * M1 + 524288);
  unsigned short* wO_all = wA_all + (size_t)NLAYERS * 2 * DINNER * DMODEL;

  // Hoisted weight casts
  cast_bf16_kernel<<<512, 256, 0, stream>>>(in_proj_w, wA_all);
  cast_bf16_kernel<<<256, 256, 0, stream>>>(out_proj_w, wO_all);

  for (int l = 0; l < NLAYERS; l++) {
    const unsigned short* wA = wA_all + (size_t)l * 2 * DINNER * DMODEL;
    const unsigned short* wO = wO_all + (size_t)l * DMODEL * DINNER;

    if (l == 0)
      embed_rms_kernel<<<2048, 256, 0, stream>>>(x, emb_w, emb_b, norm_w, h, ub);
    else
      rmsnorm_kernel<<<2048, 256, 0, stream>>>(h, norm_w + l * DMODEL, ub);

    // in_proj: split epilogue -> xc fp32 + zb bf16
    gemm_bf16<2><<<dim3(1024 / 128, 8192 / 128), 256, 0, stream>>>(
        ub, wA, xc, zb, TOK, 2 * DINNER, DMODEL);
    // conv + silu (sliding window), bf16 out
    conv_silu_kernel<<<256, 256, 0, stream>>>(
        xc, conv_w + (size_t)l * DINNER * DCONV, conv_b + (size_t)l * DINNER, xs);
    // x_proj: (8192,48) = xs_bf16 @ W^T (fp32 accum)
    gemm_bf16a<32><<<dim3(1, 8192 / 32), 256, 0, stream>>>(
        xs, x_proj_w + (size_t)l * 48 * DINNER, dbc, TOK, 48, DINNER);
    dt_kernel<<<512, 256, 0, stream>>>(
        dbc, dt_proj_w + (size_t)l * DINNER * DTRANK, dt_proj_b + (size_t)l * DINNER, delta);
    // Chunked scan
    scan_phase1<<<BB * CHUNKS * 2, 256, 0, stream>>>(
        delta, dbc, xs, A_log + (size_t)l * DINNER * DSTATE, pf, hf);
    scan_phase2<<<128, 256, 0, stream>>>(pf, hf);
    scan_phase3<<<BB * CHUNKS * 2, 256, 0, stream>>>(
        delta, dbc, xs, zb, A_log + (size_t)l * DINNER * DSTATE,
        Dp + (size_t)l * DINNER, pf, ybb);
    // out_proj (+residual): h += ybb @ wO^T
    gemm_bf16<1><<<dim3(256 / 128, 8192 / 128), 256, 0, stream>>>(
        ybb, wO, h, nullptr, TOK, DMODEL, DINNER);
  }
}

// Round 8
// 349.901 us; speedup vs baseline: 9.9158x; 1.0378x over previous
//
#include <hip/hip_runtime.h>
#include <hip/hip_bf16.h>
#include <math.h>

// Problem constants
#define BB 4
#define WW 2048
#define TOK (BB * WW)        // 8192
#define DMODEL 256
#define DINNER 512
#define DSTATE 16
#define DTRANK 16
#define DCONV 4
#define NLAYERS 2
#define CHUNKS 64
#define CLEN (WW / CHUNKS)   // 32

typedef __attribute__((ext_vector_type(8))) short short8;
typedef __attribute__((ext_vector_type(4))) float floatx4;

static __device__ __forceinline__ unsigned short f2bf(float f) {
  __hip_bfloat16 b = __float2bfloat16(f);
  return *(unsigned short*)&b;
}
static __device__ __forceinline__ float bf2f(unsigned short u) {
  union { unsigned int i; float f; } x;
  x.i = ((unsigned int)u) << 16;
  return x.f;
}

static __device__ __forceinline__ void load_lds16(const void* g, void* l) {
  __builtin_amdgcn_global_load_lds(
      (const __attribute__((address_space(1))) unsigned int*)g,
      (__attribute__((address_space(3))) unsigned int*)l, 16, 0, 0);
}

// ---------------------------------------------------------------------------
// Fused embed + RMSNorm (layer 0)
// ---------------------------------------------------------------------------
__global__ __launch_bounds__(256) void embed_rms_kernel(
    const float* __restrict__ x, const float* __restrict__ ew,
    const float* __restrict__ eb, const float* __restrict__ nw,
    float* __restrict__ h, unsigned short* __restrict__ ub) {
  int wave = threadIdx.x >> 6;
  int lane = threadIdx.x & 63;
  int tok = blockIdx.x * 4 + wave;
  int d4 = lane * 4;
  float xv = x[tok];
  float4 w = *(const float4*)&ew[d4];
  float4 b = *(const float4*)&eb[d4];
  float4 e;
  e.x = xv * w.x + b.x;
  e.y = xv * w.y + b.y;
  e.z = xv * w.z + b.z;
  e.w = xv * w.w + b.w;
  *(float4*)&h[(size_t)tok * DMODEL + d4] = e;
  float ss = e.x * e.x + e.y * e.y + e.z * e.z + e.w * e.w;
#pragma unroll
  for (int off = 32; off; off >>= 1) ss += __shfl_xor(ss, off, 64);
  float rs = rsqrtf(ss * (1.0f / 256.0f) + 1e-5f);
  float4 nv = *(const float4*)&nw[d4];
  ushort4 o;
  o.x = f2bf(e.x * rs * nv.x);
  o.y = f2bf(e.y * rs * nv.y);
  o.z = f2bf(e.z * rs * nv.z);
  o.w = f2bf(e.w * rs * nv.w);
  *(ushort4*)&ub[(size_t)tok * DMODEL + d4] = o;
}

// ---------------------------------------------------------------------------
// RMSNorm (layer >=1)
// ---------------------------------------------------------------------------
__global__ __launch_bounds__(256) void rmsnorm_kernel(
    const float* __restrict__ h, const float* __restrict__ w,
    unsigned short* __restrict__ ub) {
  int wave = threadIdx.x >> 6;
  int lane = threadIdx.x & 63;
  int tok = blockIdx.x * 4 + wave;
  const float* hp = h + (size_t)tok * DMODEL;
  float4 v = *(const float4*)&hp[lane * 4];
  float ss = v.x * v.x + v.y * v.y + v.z * v.z + v.w * v.w;
#pragma unroll
  for (int off = 32; off; off >>= 1) ss += __shfl_xor(ss, off, 64);
  float rs = rsqrtf(ss * (1.0f / 256.0f) + 1e-5f);
  float4 wv = *(const float4*)&w[lane * 4];
  ushort4 o;
  o.x = f2bf(v.x * rs * wv.x);
  o.y = f2bf(v.y * rs * wv.y);
  o.z = f2bf(v.z * rs * wv.z);
  o.w = f2bf(v.w * rs * wv.w);
  *(ushort4*)&ub[(size_t)tok * DMODEL + lane * 4] = o;
}

// ---------------------------------------------------------------------------
// Combined weight cast: in_proj (both layers) then out_proj (both layers)
// ---------------------------------------------------------------------------
#define WA_ELEMS (NLAYERS * 2 * DINNER * DMODEL)   // 1048576
#define WO_ELEMS (NLAYERS * DMODEL * DINNER)       // 524288
__global__ __launch_bounds__(256) void cast_weights_kernel(
    const float* __restrict__ wa, const float* __restrict__ wo,
    unsigned short* __restrict__ dA, unsigned short* __restrict__ dO) {
  int i = (blockIdx.x * 256 + threadIdx.x) * 4;
  if (i < WA_ELEMS) {
    float4 v = *(const float4*)&wa[i];
    ushort4 o = {f2bf(v.x), f2bf(v.y), f2bf(v.z), f2bf(v.w)};
    *(ushort4*)&dA[i] = o;
  } else {
    int j = i - WA_ELEMS;
    float4 v = *(const float4*)&wo[j];
    ushort4 o = {f2bf(v.x), f2bf(v.y), f2bf(v.z), f2bf(v.w)};
    *(ushort4*)&dO[j] = o;
  }
}

// ---------------------------------------------------------------------------
// bf16 MFMA GEMM: 128x128 tile, BK=32.
// EPI=2: in_proj split epilogue: cols <512 -> fp32 xc, cols >=512 -> bf16 zb
// ---------------------------------------------------------------------------
template <int EPI>
__global__ __launch_bounds__(256) void gemm_bf16(
    const unsigned short* __restrict__ A, const unsigned short* __restrict__ Bw,
    float* __restrict__ C, unsigned short* __restrict__ Cz,
    int M, int N, int K) {
  __shared__ unsigned short As[128 * 32];   // row-major 128 x 32, 64 B rows
  __shared__ unsigned short Bs[128 * 32];
  int tid = threadIdx.x;
  int wave = tid >> 6;
  int lane = tid & 63;
  int wm = (wave & 1) * 64;
  int wn = (wave >> 1) * 64;
  int m0 = blockIdx.y * 128;
  int n0 = blockIdx.x * 128;
  int mlane = lane & 15;
  int quad = lane >> 4;
  floatx4 acc[4][4] = {};

  for (int k0 = 0; k0 < K; k0 += 32) {
#pragma unroll
    for (int i = 0; i < 2; i++) {
      int off = i * 4096 + wave * 1024 + lane * 16;
      int row = off >> 6;
      int col = off & 63;
      load_lds16((const char*)A + ((size_t)(m0 + row) * K + k0) * 2 + col,
                 (char*)As + i * 4096 + wave * 1024);
    }
#pragma unroll
    for (int i = 0; i < 2; i++) {
      int off = i * 4096 + wave * 1024 + lane * 16;
      int row = off >> 6;
      int col = off & 63;
      load_lds16((const char*)Bw + ((size_t)(n0 + row) * K + k0) * 2 + col,
                 (char*)Bs + i * 4096 + wave * 1024);
    }
    __syncthreads();
    short8 af[4], bf[4];
#pragma unroll
    for (int i = 0; i < 4; i++)
      af[i] = *(const short8*)((const char*)As + (wm + i * 16 + mlane) * 64 + quad * 16);
#pragma unroll
    for (int j = 0; j < 4; j++)
      bf[j] = *(const short8*)((const char*)Bs + (wn + j * 16 + mlane) * 64 + quad * 16);
#pragma unroll
    for (int i = 0; i < 4; i++)
#pragma unroll
      for (int j = 0; j < 4; j++)
        acc[i][j] = __builtin_amdgcn_mfma_f32_16x16x32_bf16(af[i], bf[j], acc[i][j], 0, 0, 0);
    __syncthreads();
  }

#pragma unroll
  for (int i = 0; i < 4; i++) {
#pragma unroll
    for (int j = 0; j < 4; j++) {
      int n = n0 + wn + j * 16 + mlane;
#pragma unroll
      for (int r = 0; r < 4; r++) {
        int m = m0 + wm + i * 16 + quad * 4 + r;
        float v = acc[i][j][r];
        if (EPI == 2) {
          if (n < DINNER) C[(size_t)m * DINNER + n] = v;
          else Cz[(size_t)m * DINNER + (n - DINNER)] = f2bf(v);
        } else {
          float* p = &C[(size_t)m * N + n];
          if (EPI == 1) v += *p;
          *p = v;
        }
      }
    }
  }
}

// ---------------------------------------------------------------------------
// bf16 MFMA GEMM, 128x64 tile (for out_proj N=256 -> 256 blocks), C += A*B^T.
// 4 waves each 32x64 (2x4 mfma frags).
// ---------------------------------------------------------------------------
__global__ __launch_bounds__(256) void gemm_bf16_n64(
    const unsigned short* __restrict__ A, const unsigned short* __restrict__ Bw,
    float* __restrict__ C, int M, int N, int K) {
  __shared__ unsigned short As[128 * 32];   // 8 KB
  __shared__ unsigned short Bs[64 * 32];    // 4 KB
  int tid = threadIdx.x;
  int wave = tid >> 6;
  int lane = tid & 63;
  int wm = wave * 32;
  int m0 = blockIdx.y * 128;
  int n0 = blockIdx.x * 64;
  int mlane = lane & 15;
  int quad = lane >> 4;
  floatx4 acc[2][4] = {};

  for (int k0 = 0; k0 < K; k0 += 32) {
#pragma unroll
    for (int i = 0; i < 2; i++) {
      int off = i * 4096 + wave * 1024 + lane * 16;
      int row = off >> 6;
      int col = off & 63;
      load_lds16((const char*)A + ((size_t)(m0 + row) * K + k0) * 2 + col,
                 (char*)As + i * 4096 + wave * 1024);
    }
    {
      int off = wave * 1024 + lane * 16;
      int row = off >> 6;
      int col = off & 63;
      load_lds16((const char*)Bw + ((size_t)(n0 + row) * K + k0) * 2 + col,
                 (char*)Bs + wave * 1024);
    }
    __syncthreads();
    short8 af[2], bf[4];
#pragma unroll
    for (int i = 0; i < 2; i++)
      af[i] = *(const short8*)((const char*)As + (wm + i * 16 + mlane) * 64 + quad * 16);
#pragma unroll
    for (int j = 0; j < 4; j++)
      bf[j] = *(const short8*)((const char*)Bs + (j * 16 + mlane) * 64 + quad * 16);
#pragma unroll
    for (int i = 0; i < 2; i++)
#pragma unroll
      for (int j = 0; j < 4; j++)
        acc[i][j] = __builtin_amdgcn_mfma_f32_16x16x32_bf16(af[i], bf[j], acc[i][j], 0, 0, 0);
    __syncthreads();
  }

#pragma unroll
  for (int i = 0; i < 2; i++) {
#pragma unroll
    for (int j = 0; j < 4; j++) {
      int n = n0 + j * 16 + mlane;
#pragma unroll
      for (int r = 0; r < 4; r++) {
        int m = m0 + wm + i * 16 + quad * 4 + r;
        float* p = &C[(size_t)m * N + n];
        *p = acc[i][j][r] + *p;
      }
    }
  }
}

// ---------------------------------------------------------------------------
// x_proj GEMM: C[M,48] = A_bf16[M,512] * B_fp32[48,512]^T.  BM=32, BK=32.
// ---------------------------------------------------------------------------
template <int BM>
__global__ __launch_bounds__(256) void gemm_bf16a(
    const unsigned short* __restrict__ A, const float* __restrict__ Bw,
    float* __restrict__ C, int M, int N, int K) {
  __shared__ float As[32][BM];
  __shared__ float Bs[32][64];
  const int RP = BM / 16;          // 2
  int tid = threadIdx.x;
  int m0 = blockIdx.y * BM;
  int n0 = blockIdx.x * 64;
  int tx = tid & 15;
  int ty = tid >> 4;
  float acc[RP][4] = {};

  for (int k0 = 0; k0 < K; k0 += 32) {
    {
      int r = tid >> 3;            // 0..31
      int c = (tid & 7) * 4;
      ushort4 a = *(const ushort4*)&A[(size_t)(m0 + r) * K + k0 + c];
      As[c + 0][r] = bf2f(a.x);
      As[c + 1][r] = bf2f(a.y);
      As[c + 2][r] = bf2f(a.z);
      As[c + 3][r] = bf2f(a.w);
    }
    {
      int rb = tid >> 2;
      int cb = (tid & 3) * 8;
#pragma unroll
      for (int i = 0; i < 2; i++) {
        int col = cb + i * 4;
        float4 v = make_float4(0.f, 0.f, 0.f, 0.f);
        if (n0 + rb < N) v = *(const float4*)&Bw[(size_t)(n0 + rb) * K + k0 + col];
        Bs[col + 0][rb] = v.x;
        Bs[col + 1][rb] = v.y;
        Bs[col + 2][rb] = v.z;
        Bs[col + 3][rb] = v.w;
      }
    }
    __syncthreads();
#pragma unroll
    for (int kk = 0; kk < 32; kk++) {
      float av[RP];
#pragma unroll
      for (int i = 0; i < RP; i++) av[i] = As[kk][ty * RP + i];
      float4 b = *(const float4*)&Bs[kk][tx * 4];
      float bv[4] = {b.x, b.y, b.z, b.w};
#pragma unroll
      for (int i = 0; i < RP; i++)
#pragma unroll
        for (int j = 0; j < 4; j++) acc[i][j] = fmaf(av[i], bv[j], acc[i][j]);
    }
    __syncthreads();
  }

  int n = n0 + tx * 4;
  if (n < N) {
#pragma unroll
    for (int i = 0; i < RP; i++) {
      int m = m0 + ty * RP + i;
      float4 v = {acc[i][0], acc[i][1], acc[i][2], acc[i][3]};
      *(float4*)&C[(size_t)m * N + n] = v;
    }
  }
}

// ---------------------------------------------------------------------------
// Causal depthwise conv + SiLU, sliding-window; 4 channels x 8-token strip.
// 512 blocks for latency hiding.
// ---------------------------------------------------------------------------
__global__ __launch_bounds__(256) void conv_silu_kernel(
    const float* __restrict__ xc, const float* __restrict__ cw,
    const float* __restrict__ cb, unsigned short* __restrict__ xs) {
  int idx = blockIdx.x * 256 + threadIdx.x;    // 131072
  int c4 = (idx & 127) * 4;
  int rest = idx >> 7;
  int strip = rest & 255;
  int b = rest >> 8;
  int t0 = strip * 8;
  float wch[4][4];
#pragma unroll
  for (int c = 0; c < 4; c++) {
    float4 w = *(const float4*)&cw[(c4 + c) * DCONV];
    wch[c][0] = w.x; wch[c][1] = w.y; wch[c][2] = w.z; wch[c][3] = w.w;
  }
  float4 bias = *(const float4*)&cb[c4];
  const float* xp = xc + ((size_t)b * WW) * DINNER + c4;
  float4 xm3 = make_float4(0, 0, 0, 0), xm2 = xm3, xm1 = xm3;
  if (t0 >= 3) xm3 = *(const float4*)&xp[(size_t)(t0 - 3) * DINNER];
  if (t0 >= 2) xm2 = *(const float4*)&xp[(size_t)(t0 - 2) * DINNER];
  if (t0 >= 1) xm1 = *(const float4*)&xp[(size_t)(t0 - 1) * DINNER];
  unsigned short* op = xs + ((size_t)b * WW) * DINNER + c4;
#pragma unroll
  for (int t = t0; t < t0 + 8; t++) {
    float4 xcur = *(const float4*)&xp[(size_t)t * DINNER];
    float a0 = bias.x, a1 = bias.y, a2 = bias.z, a3 = bias.w;
    a0 = fmaf(xm3.x, wch[0][0], fmaf(xm2.x, wch[0][1], fmaf(xm1.x, wch[0][2], fmaf(xcur.x, wch[0][3], a0))));
    a1 = fmaf(xm3.y, wch[1][0], fmaf(xm2.y, wch[1][1], fmaf(xm1.y, wch[1][2], fmaf(xcur.y, wch[1][3], a1))));
    a2 = fmaf(xm3.z, wch[2][0], fmaf(xm2.z, wch[2][1], fmaf(xm1.z, wch[2][2], fmaf(xcur.z, wch[2][3], a2))));
    a3 = fmaf(xm3.w, wch[3][0], fmaf(xm2.w, wch[3][1], fmaf(xm1.w, wch[3][2], fmaf(xcur.w, wch[3][3], a3))));
    ushort4 o;
    o.x = f2bf(a0 / (1.f + __expf(-a0)));
    o.y = f2bf(a1 / (1.f + __expf(-a1)));
    o.z = f2bf(a2 / (1.f + __expf(-a2)));
    o.w = f2bf(a3 / (1.f + __expf(-a3)));
    *(ushort4*)&op[(size_t)t * DINNER] = o;
    xm3 = xm2; xm2 = xm1; xm1 = xcur;
  }
}

// ---------------------------------------------------------------------------
// Chunked selective scan with FUSED dt-projection+softplus.
// Thread owns one d-channel, 16 states in registers.  delta computed inline
// in fp32 from dbc row (wave-uniform) . dtw[d] (loop-invariant registers).
// ---------------------------------------------------------------------------
__global__ __launch_bounds__(256) void scan_phase1(
    const float* __restrict__ dbc, const unsigned short* __restrict__ xs,
    const float* __restrict__ dtw, const float* __restrict__ dtb,
    const float* __restrict__ A_log,
    float* __restrict__ Pfin, float* __restrict__ Hfin) {
  int blk = blockIdx.x;            // (b*CHUNKS + c)*2 + dblk
  int dblk = blk & 1;
  int bc = blk >> 1;
  int c = bc & (CHUNKS - 1);
  int b = bc >> 6;
  int d = dblk * 256 + threadIdx.x;
  float A[16], wt[16];
#pragma unroll
  for (int j = 0; j < 4; j++) {
    float4 v = *(const float4*)&A_log[d * DSTATE + j * 4];
    A[4 * j + 0] = -__expf(v.x);
    A[4 * j + 1] = -__expf(v.y);
    A[4 * j + 2] = -__expf(v.z);
    A[4 * j + 3] = -__expf(v.w);
    float4 q = *(const float4*)&dtw[d * DTRANK + j * 4];
    wt[4 * j + 0] = q.x; wt[4 * j + 1] = q.y;
    wt[4 * j + 2] = q.z; wt[4 * j + 3] = q.w;
  }
  float bias = dtb[d];
  float h[16], P[16];
#pragma unroll
  for (int s = 0; s < 16; s++) { h[s] = 0.f; P[s] = 1.f; }
  int t0 = c * CLEN;
  const unsigned short* up_ = xs + ((size_t)(b * WW + t0)) * DINNER + d;
  const float* bcp = dbc + ((size_t)(b * WW + t0)) * 48;
#pragma unroll 4
  for (int t = 0; t < CLEN; t++) {
    float uv = bf2f(up_[(size_t)t * DINNER]);
    float dt16[16], Bv[16];
#pragma unroll
    for (int j = 0; j < 4; j++) {
      float4 q = *(const float4*)&bcp[t * 48 + j * 4];
      dt16[4 * j + 0] = q.x; dt16[4 * j + 1] = q.y;
      dt16[4 * j + 2] = q.z; dt16[4 * j + 3] = q.w;
      float4 r = *(const float4*)&bcp[t * 48 + DTRANK + j * 4];
      Bv[4 * j + 0] = r.x; Bv[4 * j + 1] = r.y;
      Bv[4 * j + 2] = r.z; Bv[4 * j + 3] = r.w;
    }
    float s0 = bias;
#pragma unroll
    for (int r = 0; r < 16; r++) s0 = fmaf(dt16[r], wt[r], s0);
    float dv = fmaxf(s0, 0.f) + __logf(1.f + __expf(-fabsf(s0)));
    float du = dv * uv;
#pragma unroll
    for (int s = 0; s < 16; s++) {
      float e = __expf(dv * A[s]);
      P[s] *= e;
      h[s] = fmaf(e, h[s], du * Bv[s]);
    }
  }
  size_t o = ((size_t)(b * DINNER + d) * CHUNKS + c) * DSTATE;
#pragma unroll
  for (int j = 0; j < 4; j++) {
    float4 pv = {P[4 * j], P[4 * j + 1], P[4 * j + 2], P[4 * j + 3]};
    float4 hv = {h[4 * j], h[4 * j + 1], h[4 * j + 2], h[4 * j + 3]};
    *(float4*)&Pfin[o + 4 * j] = pv;
    *(float4*)&Hfin[o + 4 * j] = hv;
  }
}

// In-place: carry-in overwrites Pfin.
__global__ __launch_bounds__(256) void scan_phase2(
    float* __restrict__ Pfin, const float* __restrict__ Hfin) {
  int idx = blockIdx.x * 256 + threadIdx.x;  // 32768 = g*16+s
  int s = idx & 15;
  int g = idx >> 4;
  float h = 0.f;
#pragma unroll
  for (int c = 0; c < CHUNKS; c++) {
    size_t o = ((size_t)g * CHUNKS + c) * DSTATE + s;
    float P = Pfin[o];
    float f = Hfin[o];
    Pfin[o] = h;             // carry-in for chunk c
    h = fmaf(P, h, f);
  }
}

__global__ __launch_bounds__(256) void scan_phase3(
    const float* __restrict__ dbc, const unsigned short* __restrict__ xs,
    const unsigned short* __restrict__ zb,
    const float* __restrict__ dtw, const float* __restrict__ dtb,
    const float* __restrict__ A_log, const float* __restrict__ Dp,
    const float* __restrict__ Hin, unsigned short* __restrict__ yb) {
  int blk = blockIdx.x;
  int dblk = blk & 1;
  int bc = blk >> 1;
  int c = bc & (CHUNKS - 1);
  int b = bc >> 6;
  int d = dblk * 256 + threadIdx.x;
  float A[16], wt[16];
#pragma unroll
  for (int j = 0; j < 4; j++) {
    float4 v = *(const float4*)&A_log[d * DSTATE + j * 4];
    A[4 * j + 0] = -__expf(v.x);
    A[4 * j + 1] = -__expf(v.y);
    A[4 * j + 2] = -__expf(v.z);
    A[4 * j + 3] = -__expf(v.w);
    float4 q = *(const float4*)&dtw[d * DTRANK + j * 4];
    wt[4 * j + 0] = q.x; wt[4 * j + 1] = q.y;
    wt[4 * j + 2] = q.z; wt[4 * j + 3] = q.w;
  }
  float bias = dtb[d];
  float Dv = Dp[d];
  float h[16];
  size_t o = ((size_t)(b * DINNER + d) * CHUNKS + c) * DSTATE;
#pragma unroll
  for (int j = 0; j < 4; j++) {
    float4 hv = *(const float4*)&Hin[o + 4 * j];
    h[4 * j + 0] = hv.x; h[4 * j + 1] = hv.y;
    h[4 * j + 2] = hv.z; h[4 * j + 3] = hv.w;
  }
  int t0 = c * CLEN;
  const unsigned short* up_ = xs + ((size_t)(b * WW + t0)) * DINNER + d;
  const float* bcp = dbc + ((size_t)(b * WW + t0)) * 48;
  const unsigned short* zp = zb + ((size_t)(b * WW + t0)) * DINNER + d;
  unsigned short* yp = yb + ((size_t)(b * WW + t0)) * DINNER + d;
#pragma unroll 4
  for (int t = 0; t < CLEN; t++) {
    float uv = bf2f(up_[(size_t)t * DINNER]);
    float zv = bf2f(zp[(size_t)t * DINNER]);
    float dt16[16], Bv[16], Cv[16];
#pragma unroll
    for (int j = 0; j < 4; j++) {
      float4 q = *(const float4*)&bcp[t * 48 + j * 4];
      dt16[4 * j + 0] = q.x; dt16[4 * j + 1] = q.y;
      dt16[4 * j + 2] = q.z; dt16[4 * j + 3] = q.w;
      float4 r = *(const float4*)&bcp[t * 48 + DTRANK + j * 4];
      Bv[4 * j + 0] = r.x; Bv[4 * j + 1] = r.y;
      Bv[4 * j + 2] = r.z; Bv[4 * j + 3] = r.w;
      float4 u2 = *(const float4*)&bcp[t * 48 + DTRANK + DSTATE + j * 4];
      Cv[4 * j + 0] = u2.x; Cv[4 * j + 1] = u2.y;
      Cv[4 * j + 2] = u2.z; Cv[4 * j + 3] = u2.w;
    }
    float s0 = bias;
#pragma unroll
    for (int r = 0; r < 16; r++) s0 = fmaf(dt16[r], wt[r], s0);
    float dv = fmaxf(s0, 0.f) + __logf(1.f + __expf(-fabsf(s0)));
    float du = dv * uv;
    float p = 0.f;
#pragma unroll
    for (int s = 0; s < 16; s++) {
      float e = __expf(dv * A[s]);
      h[s] = fmaf(e, h[s], du * Bv[s]);
      p = fmaf(h[s], Cv[s], p);
    }
    float yv = fmaf(uv, Dv, p);
    yv *= zv / (1.f + __expf(-zv));
    yp[(size_t)t * DINNER] = f2bf(yv);
  }
}

// ---------------------------------------------------------------------------
extern "C" void kernel_launch(void* const* d_in, const int* in_sizes, int n_in,
                              void* d_out, int out_size, void* d_ws, size_t ws_size,
                              hipStream_t stream) {
  const float* x = (const float*)d_in[0];
  const float* emb_w = (const float*)d_in[1];
  const float* emb_b = (const float*)d_in[2];
  const float* in_proj_w = (const float*)d_in[3];
  const float* conv_w = (const float*)d_in[4];
  const float* conv_b = (const float*)d_in[5];
  const float* x_proj_w = (const float*)d_in[6];
  const float* dt_proj_w = (const float*)d_in[7];
  const float* dt_proj_b = (const float*)d_in[8];
  const float* A_log = (const float*)d_in[9];
  const float* Dp = (const float*)d_in[10];
  const float* out_proj_w = (const float*)d_in[11];
  const float* norm_w = (const float*)d_in[12];

  float* h = (float*)d_out;                       // (8192, 256)
  float* ws = (float*)d_ws;
  // Region map (float-equivalent offsets), ALL DISJOINT (ws = 268 MB):
  //   [0,1M)       : ub bf16 (TOKxDMODEL = 2M bf16)
  //   [1M,5M)      : xc fp32 (TOKxDINNER)
  //   [5M,7M)      : zb bf16 (TOKxDINNER = 4M bf16)
  //   [7M,9M)      : xs bf16
  //   [9M,9.5M)    : dbc fp32 (TOKx48 = 393216 fl)
  //   [9.5M,11.5M) : pf fp32 (2048*64*16 = 2M fl)
  //   [11.5M,13.5M): hf fp32
  //   [13.5M,15.5M): ybb bf16
  //   [15.5M,16M)  : wA_all bf16 (1048576)
  //   [16M,16.25M) : wO_all bf16 (524288)
  const size_t M1 = 1024 * 1024;
  unsigned short* ub = (unsigned short*)ws;
  float* xc = ws + 1 * M1;
  unsigned short* zb = (unsigned short*)(ws + 5 * M1);
  unsigned short* xs = (unsigned short*)(ws + 7 * M1);
  float* dbc = ws + 9 * M1;
  float* pf = ws + 9 * M1 + 524288;
  float* hf = pf + 2 * M1;
  unsigned short* ybb = (unsigned short*)(hf + 2 * M1);
  unsigned short* wA_all = (unsigned short*)(ws + 15 * M1 + 524288);
  unsigned short* wO_all = wA_all + (size_t)WA_ELEMS;

  // One combined weight-cast launch (1.5M elements / 4 per thread)
  cast_weights_kernel<<<(WA_ELEMS + WO_ELEMS) / 1024, 256, 0, stream>>>(
      in_proj_w, out_proj_w, wA_all, wO_all);

  for (int l = 0; l < NLAYERS; l++) {
    const unsigned short* wA = wA_all + (size_t)l * 2 * DINNER * DMODEL;
    const unsigned short* wO = wO_all + (size_t)l * DMODEL * DINNER;

    if (l == 0)
      embed_rms_kernel<<<2048, 256, 0, stream>>>(x, emb_w, emb_b, norm_w, h, ub);
    else
      rmsnorm_kernel<<<2048, 256, 0, stream>>>(h, norm_w + l * DMODEL, ub);

    // in_proj: split epilogue -> xc fp32 + zb bf16
    gemm_bf16<2><<<dim3(1024 / 128, 8192 / 128), 256, 0, stream>>>(
        ub, wA, xc, zb, TOK, 2 * DINNER, DMODEL);
    // conv + silu (sliding window, 8-token strips), bf16 out
    conv_silu_kernel<<<512, 256, 0, stream>>>(
        xc, conv_w + (size_t)l * DINNER * DCONV, conv_b + (size_t)l * DINNER, xs);
    // x_proj: (8192,48) = xs_bf16 @ W^T (fp32 weights/accum)
    gemm_bf16a<32><<<dim3(1, 8192 / 32), 256, 0, stream>>>(
        xs, x_proj_w + (size_t)l * 48 * DINNER, dbc, TOK, 48, DINNER);
    // Chunked scan with fused dt-projection (512 blocks each)
    scan_phase1<<<BB * CHUNKS * 2, 256, 0, stream>>>(
        dbc, xs, dt_proj_w + (size_t)l * DINNER * DTRANK,
        dt_proj_b + (size_t)l * DINNER, A_log + (size_t)l * DINNER * DSTATE,
        pf, hf);
    scan_phase2<<<128, 256, 0, stream>>>(pf, hf);
    scan_phase3<<<BB * CHUNKS * 2, 256, 0, stream>>>(
        dbc, xs, zb, dt_proj_w + (size_t)l * DINNER * DTRANK,
        dt_proj_b + (size_t)l * DINNER, A_log + (size_t)l * DINNER * DSTATE,
        Dp + (size_t)l * DINNER, pf, ybb);
    // out_proj (+residual): h += ybb @ wO^T  (128x64 tile -> 256 blocks)
    gemm_bf16_n64<<<dim3(256 / 64, 8192 / 128), 256, 0, stream>>>(
        ybb, wO, h, TOK, DMODEL, DINNER);
  }
}